// Round 12
// baseline (1797.413 us; speedup 1.0000x reference)
//
#include <hip/hip_runtime.h>

// ---------------------------------------------------------------------------
// Transformer (GateLoop-style) forward, MI355X/gfx950.  Round 12.
//  = round 11 + 8-phase deep-pipelined GEMM (T3/T4/T5, m201-style) for the
//    two perfect-grid GEMMs:
//      - logits (4096x32000x1024, grid 2000) and W1 (4096x4096x1024, grid 256)
//      - 256x256 tile, 8 waves (2Mx4N, wave tile 128x64), 512 thr
//      - LDS = 4-slot ring per operand of K-half tiles [256 rows][32 K]
//        (4 x 16KB x 2 = 128KB, 1 block/CU)
//      - phase: ds_read slot h&3 | prefetch K-half h+3 -> slot (h-1)&3 |
//        barrier | lgkmcnt(0)+sched_barrier | setprio(1) 16 MFMA setprio(0) |
//        [vmcnt(8) at pair end] | barrier.  Counted vmcnt => loads stay in
//        flight across barriers (no vmcnt(0) drain = the old ~860TF ceiling).
//    Accumulation order per output element unchanged -> bitwise identical.
//  Fused qkv|a|g (grid 768 = 3/CU perfect fit), Wo, W2 split-K: proven r11
//  kernels unchanged.  Scan path unchanged.
// ---------------------------------------------------------------------------

typedef float fx4 __attribute__((ext_vector_type(4)));
typedef _Float16 f16x8 __attribute__((ext_vector_type(8)));
typedef _Float16 f16x4 __attribute__((ext_vector_type(4)));

#define AS1 __attribute__((address_space(1)))
#define AS3 __attribute__((address_space(3)))

// ---------------------------------------------------------------- transpose
__global__ __launch_bounds__(256) void transpose_f16_kernel(
    const float* __restrict__ in, _Float16* __restrict__ out,
    int K, int N, size_t ostride)
{
    __shared__ float tile[32][33];
    const int b = blockIdx.z;
    in  += (size_t)b * K * N;
    out += (size_t)b * ostride;
    const int k0 = blockIdx.x * 32, n0 = blockIdx.y * 32;
    const int tr = threadIdx.x >> 3;
    const int tc = (threadIdx.x & 7) * 4;
    fx4 v = *(const fx4*)&in[(size_t)(k0 + tr) * N + n0 + tc];
    tile[tr][tc + 0] = v[0]; tile[tr][tc + 1] = v[1];
    tile[tr][tc + 2] = v[2]; tile[tr][tc + 3] = v[3];
    __syncthreads();
    f16x4 o;
    #pragma unroll
    for (int e = 0; e < 4; ++e) o[e] = (_Float16)tile[tc + e][tr];
    *(f16x4*)&out[(size_t)(n0 + tr) * K + k0 + tc] = o;
}

// ---------------------------------------------------------------- row RMS helper
__device__ __forceinline__ float row_rms_scale(float ss) {
    #pragma unroll
    for (int off = 32; off > 0; off >>= 1) ss += __shfl_down(ss, off, 64);
    __shared__ float wsum[4];
    if ((threadIdx.x & 63) == 0) wsum[threadIdx.x >> 6] = ss;
    __syncthreads();
    const float nrm = sqrtf(wsum[0] + wsum[1] + wsum[2] + wsum[3]);
    return 32.0f / fmaxf(nrm, 1e-12f);
}

// ---------------------------------------------------------------- embed + rms
__global__ __launch_bounds__(256) void embed_rms_kernel(
    const int* __restrict__ tokens, const float* __restrict__ emb,
    const float* __restrict__ g, float* __restrict__ x, _Float16* __restrict__ xn)
{
    const int row = blockIdx.x;
    const int t = tokens[row];
    const int c = threadIdx.x * 4;
    fx4 v = *(const fx4*)&emb[(size_t)t * 1024 + c];
    *(fx4*)&x[(size_t)row * 1024 + c] = v;
    const float scale = row_rms_scale(v[0]*v[0] + v[1]*v[1] + v[2]*v[2] + v[3]*v[3]);
    fx4 gg = *(const fx4*)&g[c];
    f16x4 o;
    #pragma unroll
    for (int e = 0; e < 4; ++e) o[e] = (_Float16)(v[e] * scale * gg[e]);
    *(f16x4*)&xn[(size_t)row * 1024 + c] = o;
}

// ---------------------------------------------------------------- rms -> fp16
__global__ __launch_bounds__(256) void rms_f16_kernel(
    const float* __restrict__ x, const float* __restrict__ g,
    _Float16* __restrict__ outh)
{
    const int row = blockIdx.x;
    const int c = threadIdx.x * 4;
    fx4 v = *(const fx4*)&x[(size_t)row * 1024 + c];
    const float scale = row_rms_scale(v[0]*v[0] + v[1]*v[1] + v[2]*v[2] + v[3]*v[3]);
    fx4 gg = *(const fx4*)&g[c];
    f16x4 o;
    #pragma unroll
    for (int e = 0; e < 4; ++e) o[e] = (_Float16)(v[e] * scale * gg[e]);
    *(f16x4*)&outh[(size_t)row * 1024 + c] = o;
}

// ---------------------------------------------------------------- scan prep
__global__ __launch_bounds__(256) void prep_qkv_kernel(
    const float* __restrict__ qkv, float* __restrict__ qT, float* __restrict__ kvT)
{
    __shared__ float tq[32][33], tkv[32][33];
    const int n0 = blockIdx.x * 32, h0 = blockIdx.y * 32, b = blockIdx.z;
    const int tr = threadIdx.x >> 3;
    const int tc = (threadIdx.x & 7) * 4;
    const float* row = qkv + ((size_t)b * 2048 + n0 + tr) * 3072;
    fx4 qv = *(const fx4*)&row[h0 + tc];
    fx4 kv = *(const fx4*)&row[1024 + h0 + tc];
    fx4 vv = *(const fx4*)&row[2048 + h0 + tc];
    #pragma unroll
    for (int e = 0; e < 4; ++e) { tq[tr][tc + e] = qv[e]; tkv[tr][tc + e] = kv[e] * vv[e]; }
    __syncthreads();
    fx4 oq, okv;
    #pragma unroll
    for (int e = 0; e < 4; ++e) { oq[e] = tq[tc + e][tr]; okv[e] = tkv[tc + e][tr]; }
    const size_t ob = ((size_t)b * 1024 + h0 + tr) * 2048 + n0 + tc;
    *(fx4*)&qT[ob] = oq;
    *(fx4*)&kvT[ob] = okv;
}

__global__ __launch_bounds__(256) void prep_a_kernel(
    const float* __restrict__ al, float* __restrict__ aReT, float* __restrict__ aImT)
{
    __shared__ float tre[32][33], tim[32][33];
    const int n0 = blockIdx.x * 32, h0 = blockIdx.y * 32, b = blockIdx.z;
    const int tr = threadIdx.x >> 3;
    const int tcf = (threadIdx.x & 7) * 8;
    const float* row = al + ((size_t)b * 2048 + n0 + tr) * 2048 + 2 * h0;
    fx4 v0 = *(const fx4*)&row[tcf];
    fx4 v1 = *(const fx4*)&row[tcf + 4];
    #pragma unroll
    for (int p = 0; p < 4; ++p) {
        float re = (p < 2) ? v0[2 * p] : v1[2 * (p - 2)];
        float im = (p < 2) ? v0[2 * p + 1] : v1[2 * (p - 2) + 1];
        float r = sqrtf(re * re + im * im);
        float sg = 1.0f / (1.0f + expf(-r));
        float a_re, a_im;
        if (r > 0.0f) { float inv = sg / r; a_re = re * inv; a_im = im * inv; }
        else          { a_re = sg; a_im = 0.0f; }
        tre[tr][tcf / 2 + p] = a_re;
        tim[tr][tcf / 2 + p] = a_im;
    }
    __syncthreads();
    const int tc = (threadIdx.x & 7) * 4;
    fx4 ore, oim;
    #pragma unroll
    for (int e = 0; e < 4; ++e) { ore[e] = tre[tc + e][tr]; oim[e] = tim[tc + e][tr]; }
    const size_t ob = ((size_t)b * 1024 + h0 + tr) * 2048 + n0 + tc;
    *(fx4*)&aReT[ob] = ore;
    *(fx4*)&aImT[ob] = oim;
}

// ---------------------------------------------------------------- gate-loop scan
__device__ __forceinline__ int pidx(int i) { return i + (i >> 5); }

__global__ __launch_bounds__(256) void scanT_kernel(
    const float* __restrict__ kvT, const float* __restrict__ aReT,
    const float* __restrict__ aImT, const float* __restrict__ qT,
    float* __restrict__ yT)
{
    const int tid = threadIdx.x;
    const size_t base = (size_t)blockIdx.x * 2048;
    __shared__ float s_re[2048 + 64], s_im[2048 + 64], s_kv[2048 + 64];

    for (int i = tid; i < 512; i += 256) {
        fx4 kv = *(const fx4*)&kvT[base + i * 4];
        fx4 re = *(const fx4*)&aReT[base + i * 4];
        fx4 im = *(const fx4*)&aImT[base + i * 4];
        #pragma unroll
        for (int e = 0; e < 4; ++e) {
            const int j = pidx(i * 4 + e);
            s_kv[j] = kv[e]; s_re[j] = re[e]; s_im[j] = im[e];
        }
    }
    __syncthreads();

    for (int d = 0; d < 11; ++d) {
        const int half = 1 << d, stride = half << 1;
        const int npairs = 2048 >> (d + 1);
        for (int i = tid; i < npairs; i += 256) {
            const int rj = pidx(i * stride + stride - 1);
            const int lj = pidx(i * stride + stride - 1 - half);
            float lre = s_re[lj], lim = s_im[lj], lkv = s_kv[lj];
            float rre = s_re[rj], rim = s_im[rj], rkv = s_kv[rj];
            s_kv[rj] = rre * lkv + rkv;
            s_re[rj] = rre * lre - rim * lim;
            s_im[rj] = rre * lim + rim * lre;
        }
        __syncthreads();
    }
    for (int d = 9; d >= 0; --d) {
        const int w = 1 << d;
        const int nupd = (2048 >> (d + 1)) - 1;
        for (int t = tid; t < nupd; t += 256) {
            const int i = t + 1;
            const int rj = pidx((2 * i + 1) * w - 1);
            const int lj = pidx(2 * i * w - 1);
            float lre = s_re[lj], lim = s_im[lj], lkv = s_kv[lj];
            float rre = s_re[rj], rim = s_im[rj], rkv = s_kv[rj];
            s_kv[rj] = rre * lkv + rkv;
            s_re[rj] = rre * lre - rim * lim;
            s_im[rj] = rre * lim + rim * lre;
        }
        __syncthreads();
    }
    for (int i = tid; i < 512; i += 256) {
        fx4 q = *(const fx4*)&qT[base + i * 4];
        fx4 o;
        #pragma unroll
        for (int e = 0; e < 4; ++e) o[e] = q[e] * s_kv[pidx(i * 4 + e)];
        *(fx4*)&yT[base + i * 4] = o;
    }
}

// ---------------------------------------------------------------- gating
__global__ __launch_bounds__(256) void gate_kernel(
    const float* __restrict__ G, const float* __restrict__ yT,
    _Float16* __restrict__ gated)
{
    __shared__ float ty[32][33];
    const int n0 = blockIdx.x * 32, h0 = blockIdx.y * 32, b = blockIdx.z;
    const int tr = threadIdx.x >> 3;
    const int tc = (threadIdx.x & 7) * 4;
    fx4 yv = *(const fx4*)&yT[((size_t)b * 1024 + h0 + tr) * 2048 + n0 + tc];
    #pragma unroll
    for (int e = 0; e < 4; ++e) ty[tr][tc + e] = yv[e];
    __syncthreads();
    const size_t grow = ((size_t)b * 2048 + n0 + tr) * 1024 + h0 + tc;
    fx4 gv = *(const fx4*)&G[grow];
    f16x4 o;
    #pragma unroll
    for (int e = 0; e < 4; ++e) {
        const float s = gv[e] / (1.0f + expf(-gv[e]));   // silu
        o[e] = (_Float16)(s * ty[tc + e][tr]);
    }
    *(f16x4*)&gated[grow] = o;
}

// ---------------------------------------------------------------- W2 combine + next-layer RMS
__global__ __launch_bounds__(256) void combine2_rms_kernel(
    const float* __restrict__ p, const float* __restrict__ bias,
    const float* __restrict__ g, float* __restrict__ x, _Float16* __restrict__ xn)
{
    const int row = blockIdx.x;
    const int c = threadIdx.x * 4;
    const size_t i = (size_t)row * 1024 + c;
    fx4 a = *(const fx4*)&p[i];
    fx4 b = *(const fx4*)&p[i + (size_t)4096 * 1024];
    fx4 xx = *(const fx4*)&x[i];
    fx4 bb = *(const fx4*)&bias[c];
    fx4 o;
    #pragma unroll
    for (int e = 0; e < 4; ++e) o[e] = xx[e] + (a[e] + b[e] + bb[e]);
    *(fx4*)&x[i] = o;
    const float scale = row_rms_scale(o[0]*o[0] + o[1]*o[1] + o[2]*o[2] + o[3]*o[3]);
    fx4 gg = *(const fx4*)&g[c];
    f16x4 oh;
    #pragma unroll
    for (int e = 0; e < 4; ++e) oh[e] = (_Float16)(o[e] * scale * gg[e]);
    *(f16x4*)&xn[i] = oh;
}

// ---------------------------------------------------------------- GEMM (2-barrier, proven)
// EPI: 0=store f32 (+bz*M*N), 2=Cf+=v, 4=Ch=f16(gelu(v+bias)),
//      6=fused routing by global col: <3072 qkv | <5120 al+bias | else G
template<int EPI, int BM, int BN, int WTM>
__global__ __launch_bounds__((BM / WTM) * (BN / 64) * 64) void gemm_kernel(
    const _Float16* __restrict__ A, const _Float16* __restrict__ Bt,
    const float* __restrict__ bias,
    float* __restrict__ Cf, float* __restrict__ Cf2, float* __restrict__ Cf3,
    _Float16* __restrict__ Ch,
    int M, int N, int K, int Kld)
{
    constexpr int NW      = BN / 64;
    constexpr int THREADS = (BM / WTM) * NW * 64;
    constexpr int M_REP   = WTM / 16;
    __shared__ __align__(16) _Float16 As[BM * 64];
    __shared__ __align__(16) _Float16 Bs[BN * 64];
    const int tid  = threadIdx.x;
    const int lane = tid & 63;
    const int wave = tid >> 6;
    const int bm = blockIdx.x, bn = blockIdx.y;
    const int bz = blockIdx.z;
    const int wm = (wave / NW) * WTM;
    const int wn = (wave % NW) * 64;

    A  += (size_t)bz * K;
    Bt += (size_t)bz * K;
    if (EPI == 0) Cf += (size_t)bz * M * N;

    fx4 acc[M_REP][4] = {};

    const size_t aRow0 = (size_t)bm * BM;
    const size_t bRow0 = (size_t)bn * BN;

    for (int k0 = 0; k0 < K; k0 += 64) {
        constexpr int QA = BM * 8 / THREADS;
        #pragma unroll
        for (int q = 0; q < QA; ++q) {
            const int chunk = q * THREADS + tid;
            const int row = chunk >> 3;
            const int slot = chunk & 7;
            const int gs = slot ^ (row & 7);
            const size_t aoff = (aRow0 + row) * (size_t)Kld + k0 + gs * 8;
            __builtin_amdgcn_global_load_lds((const AS1 void*)(A + aoff),
                (AS3 void*)((char*)As + chunk * 16), 16, 0, 0);
        }
        constexpr int QB = BN * 8 / THREADS;
        #pragma unroll
        for (int q = 0; q < QB; ++q) {
            const int chunk = q * THREADS + tid;
            const int row = chunk >> 3;
            const int slot = chunk & 7;
            const int gs = slot ^ (row & 7);
            const size_t boff = (bRow0 + row) * (size_t)Kld + k0 + gs * 8;
            __builtin_amdgcn_global_load_lds((const AS1 void*)(Bt + boff),
                (AS3 void*)((char*)Bs + chunk * 16), 16, 0, 0);
        }
        __syncthreads();

        #pragma unroll
        for (int kk = 0; kk < 2; ++kk) {
            const int sw = ((kk * 4 + (lane >> 4)) ^ (lane & 7)) * 16;
            f16x8 af[M_REP], bf[4];
            #pragma unroll
            for (int i = 0; i < M_REP; ++i) {
                const int row = wm + i * 16 + (lane & 15);
                af[i] = *(const f16x8*)((const char*)As + row * 128 + sw);
            }
            #pragma unroll
            for (int j = 0; j < 4; ++j) {
                const int row = wn + j * 16 + (lane & 15);
                bf[j] = *(const f16x8*)((const char*)Bs + row * 128 + sw);
            }
            #pragma unroll
            for (int i = 0; i < M_REP; ++i)
                #pragma unroll
                for (int j = 0; j < 4; ++j)
                    acc[i][j] = __builtin_amdgcn_mfma_f32_16x16x32_f16(
                        af[i], bf[j], acc[i][j], 0, 0, 0);
        }
        __syncthreads();
    }

    const int col_l = lane & 15, row_l = (lane >> 4) * 4;
    #pragma unroll
    for (int i = 0; i < M_REP; ++i) {
        #pragma unroll
        for (int j = 0; j < 4; ++j) {
            #pragma unroll
            for (int r = 0; r < 4; ++r) {
                const int row = bm * BM + wm + i * 16 + row_l + r;
                const int col = bn * BN + wn + j * 16 + col_l;
                const float v = acc[i][j][r];
                if (EPI == 0) {
                    Cf[(size_t)row * N + col] = v;
                } else if (EPI == 2) {
                    Cf[(size_t)row * N + col] += v;
                } else if (EPI == 4) {
                    const float t = v + bias[col];
                    const float gelu = 0.5f * t * (1.0f + erff(t * 0.70710678118654752f));
                    Ch[(size_t)row * N + col] = (_Float16)gelu;
                } else if (EPI == 6) {
                    if (col < 3072)      Cf [(size_t)row * 3072 + col] = v;
                    else if (col < 5120) Cf2[(size_t)row * 2048 + (col - 3072)] = v + bias[col - 3072];
                    else                 Cf3[(size_t)row * 1024 + (col - 5120)] = v;
                }
            }
        }
    }
}

// ---------------------------------------------------------------- GEMM (8-phase, deep pipeline)
// 256x256 tile, 8 waves (2Mx4N, wave tile 128x64), K%128==0, Kld==K.
// LDS: per operand a 4-slot ring of K-half tiles [256 rows][32 K] (16KB),
// total 128KB -> 1 block/CU.  Slot layout: line=row>>1 (128B), chunk-in-line
// c = ((row&1)*4 + granule) ^ (line&7)  (conflict-free per 8-lane group).
// Phase (K-half h, row-half rh): ds_read | prefetch K-half h+3 | barrier |
// lgkmcnt(0)+sched_barrier | setprio(1) 16 MFMA setprio(0) |
// [rh==1: vmcnt(8)] | barrier.   vmcnt(8) = 2 K-halves x 4 loads in flight.
// EPI: 0 = store f32; 4 = Ch=f16(gelu(v+bias)).
template<int EPI>
__global__ __launch_bounds__(512) void gemm8_kernel(
    const _Float16* __restrict__ A, const _Float16* __restrict__ Bt,
    const float* __restrict__ bias, float* __restrict__ Cf,
    _Float16* __restrict__ Ch, int M, int N, int K)
{
    __shared__ __align__(16) _Float16 As[4][256 * 32];
    __shared__ __align__(16) _Float16 Bs[4][256 * 32];
    const int tid = threadIdx.x, lane = tid & 63, wave = tid >> 6;
    const int bm = blockIdx.x, bn = blockIdx.y;
    const int wm = (wave >> 2) * 128;     // 2 waves along M
    const int wn = (wave & 3) * 64;       // 4 waves along N
    const size_t aRow0 = (size_t)bm * 256;
    const size_t bRow0 = (size_t)bn * 256;

    fx4 acc[8][4] = {};

    auto stageA = [&](int h) {
        _Float16* dst = &As[h & 3][0];
        const int k0 = h * 32;
        #pragma unroll
        for (int q = 0; q < 2; ++q) {
            const int ch = q * 512 + tid;
            const int line = ch >> 3, cslot = ch & 7;
            const int u = cslot ^ (line & 7);
            const int row = line * 2 + (u >> 2);
            const size_t off = (aRow0 + row) * (size_t)K + k0 + (u & 3) * 8;
            __builtin_amdgcn_global_load_lds((const AS1 void*)(A + off),
                (AS3 void*)((char*)dst + ch * 16), 16, 0, 0);
        }
    };
    auto stageB = [&](int h) {
        _Float16* dst = &Bs[h & 3][0];
        const int k0 = h * 32;
        #pragma unroll
        for (int q = 0; q < 2; ++q) {
            const int ch = q * 512 + tid;
            const int line = ch >> 3, cslot = ch & 7;
            const int u = cslot ^ (line & 7);
            const int row = line * 2 + (u >> 2);
            const size_t off = (bRow0 + row) * (size_t)K + k0 + (u & 3) * 8;
            __builtin_amdgcn_global_load_lds((const AS1 void*)(Bt + off),
                (AS3 void*)((char*)dst + ch * 16), 16, 0, 0);
        }
    };
    const int g0 = lane >> 4;             // k-granule of this lane's fragment
    auto rdA = [&](int slot, int fi) -> f16x8 {
        const int r = wm + fi * 16 + (lane & 15);
        const int byte = (r >> 1) * 128 + ((((r & 1) << 2) + g0) ^ ((r >> 1) & 7)) * 16;
        return *(const f16x8*)((const char*)&As[slot][0] + byte);
    };
    auto rdB = [&](int slot, int j) -> f16x8 {
        const int r = wn + j * 16 + (lane & 15);
        const int byte = (r >> 1) * 128 + ((((r & 1) << 2) + g0) ^ ((r >> 1) & 7)) * 16;
        return *(const f16x8*)((const char*)&Bs[slot][0] + byte);
    };

    // prologue: stage K-halves 0,1,2 (12 loads/wave); need K-half 0 -> vmcnt(8)
    stageA(0); stageB(0); stageA(1); stageB(1); stageA(2); stageB(2);
    asm volatile("s_waitcnt vmcnt(8)" ::: "memory");
    __builtin_amdgcn_s_barrier();

    const int nH = K >> 5;                // K-halves of 32
    for (int h = 0; h < nH; ++h) {
        const int slot = h & 3;
        f16x8 bf[4];
        #pragma unroll
        for (int rh = 0; rh < 2; ++rh) {
            f16x8 af[4];
            #pragma unroll
            for (int i = 0; i < 4; ++i) af[i] = rdA(slot, rh * 4 + i);
            if (rh == 0) {
                #pragma unroll
                for (int j = 0; j < 4; ++j) bf[j] = rdB(slot, j);
                stageA(h + 3);            // beyond-K stages read in-ws garbage, land in dead slot
            } else {
                stageB(h + 3);
            }
            __builtin_amdgcn_s_barrier();
            asm volatile("s_waitcnt lgkmcnt(0)" ::: "memory");
            __builtin_amdgcn_sched_barrier(0);
            __builtin_amdgcn_s_setprio(1);
            #pragma unroll
            for (int i = 0; i < 4; ++i)
                #pragma unroll
                for (int j = 0; j < 4; ++j)
                    acc[rh * 4 + i][j] = __builtin_amdgcn_mfma_f32_16x16x32_f16(
                        af[i], bf[j], acc[rh * 4 + i][j], 0, 0, 0);
            __builtin_amdgcn_s_setprio(0);
            if (rh == 1) asm volatile("s_waitcnt vmcnt(8)" ::: "memory");
            __builtin_amdgcn_s_barrier();
        }
    }

    // epilogue: C/D layout col=lane&15, row=(lane>>4)*4+r
    const int col_l = lane & 15, row_l = (lane >> 4) * 4;
    #pragma unroll
    for (int i = 0; i < 8; ++i) {
        #pragma unroll
        for (int j = 0; j < 4; ++j) {
            #pragma unroll
            for (int r = 0; r < 4; ++r) {
                const int row = bm * 256 + wm + i * 16 + row_l + r;
                const int col = bn * 256 + wn + j * 16 + col_l;
                const float v = acc[i][j][r];
                if (EPI == 0) {
                    Cf[(size_t)row * N + col] = v;
                } else if (EPI == 4) {
                    const float t = v + bias[col];
                    const float gelu = 0.5f * t * (1.0f + erff(t * 0.70710678118654752f));
                    Ch[(size_t)row * N + col] = (_Float16)gelu;
                }
            }
        }
    }
}

// ---------------------------------------------------------------- host
extern "C" void kernel_launch(void* const* d_in, const int* in_sizes, int n_in,
                              void* d_out, int out_size, void* d_ws, size_t ws_size,
                              hipStream_t stream)
{
    const int*   tokens = (const int*)d_in[0];
    const float* emb  = (const float*)d_in[1];
    const float* g1   = (const float*)d_in[2];
    const float* Wqkv = (const float*)d_in[3];
    const float* Wa   = (const float*)d_in[4];
    const float* ba   = (const float*)d_in[5];
    const float* Wg   = (const float*)d_in[6];
    const float* Wo   = (const float*)d_in[7];
    const float* g2   = (const float*)d_in[8];
    const float* W1   = (const float*)d_in[9];
    const float* b1   = (const float*)d_in[10];
    const float* W2   = (const float*)d_in[11];
    const float* b2   = (const float*)d_in[12];
    const float* gf   = (const float*)d_in[13];
    const float* Wl   = (const float*)d_in[14];
    float* out = (float*)d_out;

    char* ws = (char*)d_ws;
    size_t off = 0;
    auto take = [&](size_t bytes) {
        char* p = ws + off; off += (bytes + 255) & ~(size_t)255; return p;
    };

    _Float16* wcat = (_Float16*)take((size_t)4 * 6144 * 1024 * 2);
    _Float16* wo   = (_Float16*)take((size_t)4 * 1024 * 1024 * 2);
    _Float16* w1   = (_Float16*)take((size_t)4 * 4096 * 1024 * 2);
    _Float16* w2   = (_Float16*)take((size_t)4 * 1024 * 4096 * 2);
    char*     wlRegion = take((size_t)64 << 20);
    _Float16* wl   = (_Float16*)wlRegion;
    float*    x    = (float*)take((size_t)4096 * 1024 * 4);
    _Float16* xn   = (_Float16*)take((size_t)4096 * 1024 * 2);
    float*    qkvb = (float*)take((size_t)4096 * 3072 * 4);
    float*    alb  = (float*)take((size_t)4096 * 2048 * 4);
    float*    G    = (float*)take((size_t)4096 * 1024 * 4);

    float* qT   = (float*)wlRegion;
    float* kvT  = (float*)(wlRegion + ((size_t)16 << 20));
    float* aReT = (float*)(wlRegion + ((size_t)32 << 20));
    float* aImT = (float*)(wlRegion + ((size_t)48 << 20));
    float*    yT    = alb;
    _Float16* gated = (_Float16*)((char*)alb + ((size_t)16 << 20));
    _Float16* h     = (_Float16*)qkvb;
    float*    part  = alb;

    const dim3 blk(256);

    transpose_f16_kernel<<<dim3(32,  96, 4), blk, 0, stream>>>(Wqkv, wcat,               1024, 3072, (size_t)6144 * 1024);
    transpose_f16_kernel<<<dim3(32,  64, 4), blk, 0, stream>>>(Wa,   wcat + 3072 * 1024, 1024, 2048, (size_t)6144 * 1024);
    transpose_f16_kernel<<<dim3(32,  32, 4), blk, 0, stream>>>(Wg,   wcat + 5120 * 1024, 1024, 1024, (size_t)6144 * 1024);
    transpose_f16_kernel<<<dim3(32,  32, 4), blk, 0, stream>>>(Wo,   wo,  1024, 1024, (size_t)1024 * 1024);
    transpose_f16_kernel<<<dim3(32, 128, 4), blk, 0, stream>>>(W1,   w1,  1024, 4096, (size_t)4096 * 1024);
    transpose_f16_kernel<<<dim3(128, 32, 4), blk, 0, stream>>>(W2,   w2,  4096, 1024, (size_t)1024 * 4096);

    embed_rms_kernel<<<4096, blk, 0, stream>>>(tokens, emb, g1, x, xn);

    for (int i = 0; i < 4; ++i) {
        gemm_kernel<6, 256, 128, 64><<<dim3(16, 48), dim3(512), 0, stream>>>(
            xn, wcat + (size_t)i * 6144 * 1024, ba + i * 2048,
            qkvb, alb, G, nullptr, 4096, 6144, 1024, 1024);
        prep_qkv_kernel<<<dim3(64, 32, 2), blk, 0, stream>>>(qkvb, qT, kvT);
        prep_a_kernel<<<dim3(64, 32, 2), blk, 0, stream>>>(alb, aReT, aImT);
        scanT_kernel<<<2048, blk, 0, stream>>>(kvT, aReT, aImT, qT, yT);
        gate_kernel<<<dim3(64, 32, 2), blk, 0, stream>>>(G, yT, gated);
        gemm_kernel<2, 128, 128, 64><<<dim3(32, 8), blk, 0, stream>>>(
            gated, wo + (size_t)i * 1024 * 1024, nullptr,
            x, nullptr, nullptr, nullptr, 4096, 1024, 1024, 1024);
        rms_f16_kernel<<<4096, blk, 0, stream>>>(x, g2 + i * 1024, xn);
        // W1: 8-phase (grid 256 = exactly 1 block/CU)
        gemm8_kernel<4><<<dim3(16, 16), dim3(512), 0, stream>>>(
            xn, w1 + (size_t)i * 4096 * 1024, b1 + i * 4096,
            nullptr, h, 4096, 4096, 1024);
        gemm_kernel<0, 256, 128, 64><<<dim3(16, 8, 2), dim3(512), 0, stream>>>(
            h, w2 + (size_t)i * 1024 * 4096, nullptr,
            part, nullptr, nullptr, nullptr, 4096, 1024, 2048, 4096);
        const float* gnext = (i < 3) ? (g1 + (i + 1) * 1024) : gf;
        combine2_rms_kernel<<<4096, blk, 0, stream>>>(part, b2 + i * 1024, gnext, x, xn);
    }

    transpose_f16_kernel<<<dim3(32, 1000, 1), blk, 0, stream>>>(Wl, wl, 1024, 32000, 0);

    // logits: 8-phase deep-pipelined GEMM
    gemm8_kernel<0><<<dim3(16, 125), dim3(512), 0, stream>>>(
        xn, wl, nullptr, out, nullptr, 4096, 32000, 1024);
}

// Round 13
// 1655.157 us; speedup vs baseline: 1.0859x; 1.0859x over previous
//
#include <hip/hip_runtime.h>

// ---------------------------------------------------------------------------
// Transformer (GateLoop-style) forward, MI355X/gfx950.  Round 13.
//  = round 11 (proven 2-barrier GEMMs everywhere) except LOGITS runs a
//    ring-3 counted-vmcnt pipeline designed around the r12 failure analysis:
//      r12 failed because 128KB LDS -> 1 block/CU: vmcnt stall (~300cyc,
//      loads forced ~620cyc after issue vs ~900cyc HBM latency) had no
//      second block to hide it.  Fix: 256x128 tile, 8 waves, ring of 3
//      K-half slots (A 16KB + B 8KB)x3 = 72KB -> 2 blocks/CU, so the
//      counted-vmcnt pipeline AND inter-block overlap coexist.
//    Phase per K-half(32): {8 ds_read | stage(h+2): 3 gload_lds |
//      lgkmcnt(0)+sched_barrier | setprio(1) 16 MFMA setprio(0) |
//      vmcnt(3) | s_barrier}.  One barrier/phase; slot (h+2)%3 being
//      overwritten completed its reads before the barrier ending phase h-1.
//    K-offset order per output unchanged -> bitwise identical numerics.
// ---------------------------------------------------------------------------

typedef float fx4 __attribute__((ext_vector_type(4)));
typedef _Float16 f16x8 __attribute__((ext_vector_type(8)));
typedef _Float16 f16x4 __attribute__((ext_vector_type(4)));

#define AS1 __attribute__((address_space(1)))
#define AS3 __attribute__((address_space(3)))

// ---------------------------------------------------------------- transpose
__global__ __launch_bounds__(256) void transpose_f16_kernel(
    const float* __restrict__ in, _Float16* __restrict__ out,
    int K, int N, size_t ostride)
{
    __shared__ float tile[32][33];
    const int b = blockIdx.z;
    in  += (size_t)b * K * N;
    out += (size_t)b * ostride;
    const int k0 = blockIdx.x * 32, n0 = blockIdx.y * 32;
    const int tr = threadIdx.x >> 3;
    const int tc = (threadIdx.x & 7) * 4;
    fx4 v = *(const fx4*)&in[(size_t)(k0 + tr) * N + n0 + tc];
    tile[tr][tc + 0] = v[0]; tile[tr][tc + 1] = v[1];
    tile[tr][tc + 2] = v[2]; tile[tr][tc + 3] = v[3];
    __syncthreads();
    f16x4 o;
    #pragma unroll
    for (int e = 0; e < 4; ++e) o[e] = (_Float16)tile[tc + e][tr];
    *(f16x4*)&out[(size_t)(n0 + tr) * K + k0 + tc] = o;
}

// ---------------------------------------------------------------- row RMS helper
__device__ __forceinline__ float row_rms_scale(float ss) {
    #pragma unroll
    for (int off = 32; off > 0; off >>= 1) ss += __shfl_down(ss, off, 64);
    __shared__ float wsum[4];
    if ((threadIdx.x & 63) == 0) wsum[threadIdx.x >> 6] = ss;
    __syncthreads();
    const float nrm = sqrtf(wsum[0] + wsum[1] + wsum[2] + wsum[3]);
    return 32.0f / fmaxf(nrm, 1e-12f);
}

// ---------------------------------------------------------------- embed + rms
__global__ __launch_bounds__(256) void embed_rms_kernel(
    const int* __restrict__ tokens, const float* __restrict__ emb,
    const float* __restrict__ g, float* __restrict__ x, _Float16* __restrict__ xn)
{
    const int row = blockIdx.x;
    const int t = tokens[row];
    const int c = threadIdx.x * 4;
    fx4 v = *(const fx4*)&emb[(size_t)t * 1024 + c];
    *(fx4*)&x[(size_t)row * 1024 + c] = v;
    const float scale = row_rms_scale(v[0]*v[0] + v[1]*v[1] + v[2]*v[2] + v[3]*v[3]);
    fx4 gg = *(const fx4*)&g[c];
    f16x4 o;
    #pragma unroll
    for (int e = 0; e < 4; ++e) o[e] = (_Float16)(v[e] * scale * gg[e]);
    *(f16x4*)&xn[(size_t)row * 1024 + c] = o;
}

// ---------------------------------------------------------------- rms -> fp16
__global__ __launch_bounds__(256) void rms_f16_kernel(
    const float* __restrict__ x, const float* __restrict__ g,
    _Float16* __restrict__ outh)
{
    const int row = blockIdx.x;
    const int c = threadIdx.x * 4;
    fx4 v = *(const fx4*)&x[(size_t)row * 1024 + c];
    const float scale = row_rms_scale(v[0]*v[0] + v[1]*v[1] + v[2]*v[2] + v[3]*v[3]);
    fx4 gg = *(const fx4*)&g[c];
    f16x4 o;
    #pragma unroll
    for (int e = 0; e < 4; ++e) o[e] = (_Float16)(v[e] * scale * gg[e]);
    *(f16x4*)&outh[(size_t)row * 1024 + c] = o;
}

// ---------------------------------------------------------------- scan prep
__global__ __launch_bounds__(256) void prep_qkv_kernel(
    const float* __restrict__ qkv, float* __restrict__ qT, float* __restrict__ kvT)
{
    __shared__ float tq[32][33], tkv[32][33];
    const int n0 = blockIdx.x * 32, h0 = blockIdx.y * 32, b = blockIdx.z;
    const int tr = threadIdx.x >> 3;
    const int tc = (threadIdx.x & 7) * 4;
    const float* row = qkv + ((size_t)b * 2048 + n0 + tr) * 3072;
    fx4 qv = *(const fx4*)&row[h0 + tc];
    fx4 kv = *(const fx4*)&row[1024 + h0 + tc];
    fx4 vv = *(const fx4*)&row[2048 + h0 + tc];
    #pragma unroll
    for (int e = 0; e < 4; ++e) { tq[tr][tc + e] = qv[e]; tkv[tr][tc + e] = kv[e] * vv[e]; }
    __syncthreads();
    fx4 oq, okv;
    #pragma unroll
    for (int e = 0; e < 4; ++e) { oq[e] = tq[tc + e][tr]; okv[e] = tkv[tc + e][tr]; }
    const size_t ob = ((size_t)b * 1024 + h0 + tr) * 2048 + n0 + tc;
    *(fx4*)&qT[ob] = oq;
    *(fx4*)&kvT[ob] = okv;
}

__global__ __launch_bounds__(256) void prep_a_kernel(
    const float* __restrict__ al, float* __restrict__ aReT, float* __restrict__ aImT)
{
    __shared__ float tre[32][33], tim[32][33];
    const int n0 = blockIdx.x * 32, h0 = blockIdx.y * 32, b = blockIdx.z;
    const int tr = threadIdx.x >> 3;
    const int tcf = (threadIdx.x & 7) * 8;
    const float* row = al + ((size_t)b * 2048 + n0 + tr) * 2048 + 2 * h0;
    fx4 v0 = *(const fx4*)&row[tcf];
    fx4 v1 = *(const fx4*)&row[tcf + 4];
    #pragma unroll
    for (int p = 0; p < 4; ++p) {
        float re = (p < 2) ? v0[2 * p] : v1[2 * (p - 2)];
        float im = (p < 2) ? v0[2 * p + 1] : v1[2 * (p - 2) + 1];
        float r = sqrtf(re * re + im * im);
        float sg = 1.0f / (1.0f + expf(-r));
        float a_re, a_im;
        if (r > 0.0f) { float inv = sg / r; a_re = re * inv; a_im = im * inv; }
        else          { a_re = sg; a_im = 0.0f; }
        tre[tr][tcf / 2 + p] = a_re;
        tim[tr][tcf / 2 + p] = a_im;
    }
    __syncthreads();
    const int tc = (threadIdx.x & 7) * 4;
    fx4 ore, oim;
    #pragma unroll
    for (int e = 0; e < 4; ++e) { ore[e] = tre[tc + e][tr]; oim[e] = tim[tc + e][tr]; }
    const size_t ob = ((size_t)b * 1024 + h0 + tr) * 2048 + n0 + tc;
    *(fx4*)&aReT[ob] = ore;
    *(fx4*)&aImT[ob] = oim;
}

// ---------------------------------------------------------------- gate-loop scan
__device__ __forceinline__ int pidx(int i) { return i + (i >> 5); }

__global__ __launch_bounds__(256) void scanT_kernel(
    const float* __restrict__ kvT, const float* __restrict__ aReT,
    const float* __restrict__ aImT, const float* __restrict__ qT,
    float* __restrict__ yT)
{
    const int tid = threadIdx.x;
    const size_t base = (size_t)blockIdx.x * 2048;
    __shared__ float s_re[2048 + 64], s_im[2048 + 64], s_kv[2048 + 64];

    for (int i = tid; i < 512; i += 256) {
        fx4 kv = *(const fx4*)&kvT[base + i * 4];
        fx4 re = *(const fx4*)&aReT[base + i * 4];
        fx4 im = *(const fx4*)&aImT[base + i * 4];
        #pragma unroll
        for (int e = 0; e < 4; ++e) {
            const int j = pidx(i * 4 + e);
            s_kv[j] = kv[e]; s_re[j] = re[e]; s_im[j] = im[e];
        }
    }
    __syncthreads();

    for (int d = 0; d < 11; ++d) {
        const int half = 1 << d, stride = half << 1;
        const int npairs = 2048 >> (d + 1);
        for (int i = tid; i < npairs; i += 256) {
            const int rj = pidx(i * stride + stride - 1);
            const int lj = pidx(i * stride + stride - 1 - half);
            float lre = s_re[lj], lim = s_im[lj], lkv = s_kv[lj];
            float rre = s_re[rj], rim = s_im[rj], rkv = s_kv[rj];
            s_kv[rj] = rre * lkv + rkv;
            s_re[rj] = rre * lre - rim * lim;
            s_im[rj] = rre * lim + rim * lre;
        }
        __syncthreads();
    }
    for (int d = 9; d >= 0; --d) {
        const int w = 1 << d;
        const int nupd = (2048 >> (d + 1)) - 1;
        for (int t = tid; t < nupd; t += 256) {
            const int i = t + 1;
            const int rj = pidx((2 * i + 1) * w - 1);
            const int lj = pidx(2 * i * w - 1);
            float lre = s_re[lj], lim = s_im[lj], lkv = s_kv[lj];
            float rre = s_re[rj], rim = s_im[rj], rkv = s_kv[rj];
            s_kv[rj] = rre * lkv + rkv;
            s_re[rj] = rre * lre - rim * lim;
            s_im[rj] = rre * lim + rim * lre;
        }
        __syncthreads();
    }
    for (int i = tid; i < 512; i += 256) {
        fx4 q = *(const fx4*)&qT[base + i * 4];
        fx4 o;
        #pragma unroll
        for (int e = 0; e < 4; ++e) o[e] = q[e] * s_kv[pidx(i * 4 + e)];
        *(fx4*)&yT[base + i * 4] = o;
    }
}

// ---------------------------------------------------------------- gating
__global__ __launch_bounds__(256) void gate_kernel(
    const float* __restrict__ G, const float* __restrict__ yT,
    _Float16* __restrict__ gated)
{
    __shared__ float ty[32][33];
    const int n0 = blockIdx.x * 32, h0 = blockIdx.y * 32, b = blockIdx.z;
    const int tr = threadIdx.x >> 3;
    const int tc = (threadIdx.x & 7) * 4;
    fx4 yv = *(const fx4*)&yT[((size_t)b * 1024 + h0 + tr) * 2048 + n0 + tc];
    #pragma unroll
    for (int e = 0; e < 4; ++e) ty[tr][tc + e] = yv[e];
    __syncthreads();
    const size_t grow = ((size_t)b * 2048 + n0 + tr) * 1024 + h0 + tc;
    fx4 gv = *(const fx4*)&G[grow];
    f16x4 o;
    #pragma unroll
    for (int e = 0; e < 4; ++e) {
        const float s = gv[e] / (1.0f + expf(-gv[e]));   // silu
        o[e] = (_Float16)(s * ty[tc + e][tr]);
    }
    *(f16x4*)&gated[grow] = o;
}

// ---------------------------------------------------------------- W2 combine + next-layer RMS
__global__ __launch_bounds__(256) void combine2_rms_kernel(
    const float* __restrict__ p, const float* __restrict__ bias,
    const float* __restrict__ g, float* __restrict__ x, _Float16* __restrict__ xn)
{
    const int row = blockIdx.x;
    const int c = threadIdx.x * 4;
    const size_t i = (size_t)row * 1024 + c;
    fx4 a = *(const fx4*)&p[i];
    fx4 b = *(const fx4*)&p[i + (size_t)4096 * 1024];
    fx4 xx = *(const fx4*)&x[i];
    fx4 bb = *(const fx4*)&bias[c];
    fx4 o;
    #pragma unroll
    for (int e = 0; e < 4; ++e) o[e] = xx[e] + (a[e] + b[e] + bb[e]);
    *(fx4*)&x[i] = o;
    const float scale = row_rms_scale(o[0]*o[0] + o[1]*o[1] + o[2]*o[2] + o[3]*o[3]);
    fx4 gg = *(const fx4*)&g[c];
    f16x4 oh;
    #pragma unroll
    for (int e = 0; e < 4; ++e) oh[e] = (_Float16)(o[e] * scale * gg[e]);
    *(f16x4*)&xn[i] = oh;
}

// ---------------------------------------------------------------- GEMM (2-barrier, proven)
// EPI: 0=store f32 (+bz*M*N), 2=Cf+=v, 4=Ch=f16(gelu(v+bias)),
//      6=fused routing by global col: <3072 qkv | <5120 al+bias | else G
template<int EPI, int BM, int BN, int WTM>
__global__ __launch_bounds__((BM / WTM) * (BN / 64) * 64) void gemm_kernel(
    const _Float16* __restrict__ A, const _Float16* __restrict__ Bt,
    const float* __restrict__ bias,
    float* __restrict__ Cf, float* __restrict__ Cf2, float* __restrict__ Cf3,
    _Float16* __restrict__ Ch,
    int M, int N, int K, int Kld)
{
    constexpr int NW      = BN / 64;
    constexpr int THREADS = (BM / WTM) * NW * 64;
    constexpr int M_REP   = WTM / 16;
    __shared__ __align__(16) _Float16 As[BM * 64];
    __shared__ __align__(16) _Float16 Bs[BN * 64];
    const int tid  = threadIdx.x;
    const int lane = tid & 63;
    const int wave = tid >> 6;
    const int bm = blockIdx.x, bn = blockIdx.y;
    const int bz = blockIdx.z;
    const int wm = (wave / NW) * WTM;
    const int wn = (wave % NW) * 64;

    A  += (size_t)bz * K;
    Bt += (size_t)bz * K;
    if (EPI == 0) Cf += (size_t)bz * M * N;

    fx4 acc[M_REP][4] = {};

    const size_t aRow0 = (size_t)bm * BM;
    const size_t bRow0 = (size_t)bn * BN;

    for (int k0 = 0; k0 < K; k0 += 64) {
        constexpr int QA = BM * 8 / THREADS;
        #pragma unroll
        for (int q = 0; q < QA; ++q) {
            const int chunk = q * THREADS + tid;
            const int row = chunk >> 3;
            const int slot = chunk & 7;
            const int gs = slot ^ (row & 7);
            const size_t aoff = (aRow0 + row) * (size_t)Kld + k0 + gs * 8;
            __builtin_amdgcn_global_load_lds((const AS1 void*)(A + aoff),
                (AS3 void*)((char*)As + chunk * 16), 16, 0, 0);
        }
        constexpr int QB = BN * 8 / THREADS;
        #pragma unroll
        for (int q = 0; q < QB; ++q) {
            const int chunk = q * THREADS + tid;
            const int row = chunk >> 3;
            const int slot = chunk & 7;
            const int gs = slot ^ (row & 7);
            const size_t boff = (bRow0 + row) * (size_t)Kld + k0 + gs * 8;
            __builtin_amdgcn_global_load_lds((const AS1 void*)(Bt + boff),
                (AS3 void*)((char*)Bs + chunk * 16), 16, 0, 0);
        }
        __syncthreads();

        #pragma unroll
        for (int kk = 0; kk < 2; ++kk) {
            const int sw = ((kk * 4 + (lane >> 4)) ^ (lane & 7)) * 16;
            f16x8 af[M_REP], bf[4];
            #pragma unroll
            for (int i = 0; i < M_REP; ++i) {
                const int row = wm + i * 16 + (lane & 15);
                af[i] = *(const f16x8*)((const char*)As + row * 128 + sw);
            }
            #pragma unroll
            for (int j = 0; j < 4; ++j) {
                const int row = wn + j * 16 + (lane & 15);
                bf[j] = *(const f16x8*)((const char*)Bs + row * 128 + sw);
            }
            #pragma unroll
            for (int i = 0; i < M_REP; ++i)
                #pragma unroll
                for (int j = 0; j < 4; ++j)
                    acc[i][j] = __builtin_amdgcn_mfma_f32_16x16x32_f16(
                        af[i], bf[j], acc[i][j], 0, 0, 0);
        }
        __syncthreads();
    }

    const int col_l = lane & 15, row_l = (lane >> 4) * 4;
    #pragma unroll
    for (int i = 0; i < M_REP; ++i) {
        #pragma unroll
        for (int j = 0; j < 4; ++j) {
            #pragma unroll
            for (int r = 0; r < 4; ++r) {
                const int row = bm * BM + wm + i * 16 + row_l + r;
                const int col = bn * BN + wn + j * 16 + col_l;
                const float v = acc[i][j][r];
                if (EPI == 0) {
                    Cf[(size_t)row * N + col] = v;
                } else if (EPI == 2) {
                    Cf[(size_t)row * N + col] += v;
                } else if (EPI == 4) {
                    const float t = v + bias[col];
                    const float gelu = 0.5f * t * (1.0f + erff(t * 0.70710678118654752f));
                    Ch[(size_t)row * N + col] = (_Float16)gelu;
                } else if (EPI == 6) {
                    if (col < 3072)      Cf [(size_t)row * 3072 + col] = v;
                    else if (col < 5120) Cf2[(size_t)row * 2048 + (col - 3072)] = v + bias[col - 3072];
                    else                 Cf3[(size_t)row * 1024 + (col - 5120)] = v;
                }
            }
        }
    }
}

// ---------------------------------------------------------------- GEMM (ring-3 pipeline, logits)
// 256x128 tile, 8 waves (wave tile 64x64), ring of 3 K-half(32) slots:
// A slot [256][32] 16KB, B slot [128][32] 8KB -> 72KB total -> 2 blocks/CU.
// Slot layout: line(128B) = 2 rows; chunk u = (slot7 ^ line&7); row = 2*line
// + (u>>2); k-granule = u&3 (2-way bank aliasing on reads = free, m136).
// Phase h: {8 ds_read slot h%3 | stage(h+2)->slot (h+2)%3 (2A+1B loads) |
//  lgkmcnt(0)+sched_barrier | setprio(1) 16 MFMA setprio(0) | vmcnt(3) |
//  s_barrier}.  vmcnt(3): outstanding = (h+1):3 + (h+2):3 -> retires h+1.
// Hazards: slot (h+2)%3 reads completed before barrier ending h-1 (issue is
// after it); slot h+1 gated by per-wave vmcnt(3) + barrier.  Beyond-K stage
// reads (h+2 >= nH) stay inside ws (xn pad / wlRegion 64MiB > wl 62.5MiB).
__global__ __launch_bounds__(512) void gemm_ring3_kernel(
    const _Float16* __restrict__ A, const _Float16* __restrict__ Bt,
    float* __restrict__ Cf, int M, int N, int K)
{
    __shared__ __align__(16) _Float16 As[3][256 * 32];
    __shared__ __align__(16) _Float16 Bs[3][128 * 32];
    const int tid = threadIdx.x, lane = tid & 63, wave = tid >> 6;
    const int bm = blockIdx.x, bn = blockIdx.y;
    const int wm = (wave >> 1) * 64, wn = (wave & 1) * 64;
    const size_t aRow0 = (size_t)bm * 256, bRow0 = (size_t)bn * 128;

    fx4 acc[4][4] = {};

    auto stage = [&](int h) {
        const int slot = h % 3;
        const int k0 = h * 32;
        #pragma unroll
        for (int q = 0; q < 2; ++q) {                  // A: 1024 chunks, 2/thread
            const int ch = q * 512 + tid;
            const int line = ch >> 3;
            const int u = (ch & 7) ^ (line & 7);
            const int row = line * 2 + (u >> 2);
            const size_t off = (aRow0 + row) * (size_t)K + k0 + (u & 3) * 8;
            __builtin_amdgcn_global_load_lds((const AS1 void*)(A + off),
                (AS3 void*)((char*)&As[slot][0] + ch * 16), 16, 0, 0);
        }
        {                                              // B: 512 chunks, 1/thread
            const int ch = tid;
            const int line = ch >> 3;
            const int u = (ch & 7) ^ (line & 7);
            const int row = line * 2 + (u >> 2);
            const size_t off = (bRow0 + row) * (size_t)K + k0 + (u & 3) * 8;
            __builtin_amdgcn_global_load_lds((const AS1 void*)(Bt + off),
                (AS3 void*)((char*)&Bs[slot][0] + ch * 16), 16, 0, 0);
        }
    };
    const int g0 = lane >> 4;
    auto ldoff = [&](int r) -> int {
        return (r >> 1) * 128 + ((((r & 1) << 2) + g0) ^ ((r >> 1) & 7)) * 16;
    };

    stage(0); stage(1);
    asm volatile("s_waitcnt vmcnt(3)" ::: "memory");   // slot 0 landed
    __builtin_amdgcn_s_barrier();

    const int nH = K >> 5;
    for (int h = 0; h < nH; ++h) {
        const int slot = h % 3;
        f16x8 af[4], bf[4];
        #pragma unroll
        for (int i = 0; i < 4; ++i)
            af[i] = *(const f16x8*)((const char*)&As[slot][0] + ldoff(wm + i * 16 + (lane & 15)));
        #pragma unroll
        for (int j = 0; j < 4; ++j)
            bf[j] = *(const f16x8*)((const char*)&Bs[slot][0] + ldoff(wn + j * 16 + (lane & 15)));
        stage(h + 2);
        asm volatile("s_waitcnt lgkmcnt(0)" ::: "memory");
        __builtin_amdgcn_sched_barrier(0);             // rule #18: pin MFMA after lgkm wait
        __builtin_amdgcn_s_setprio(1);
        #pragma unroll
        for (int i = 0; i < 4; ++i)
            #pragma unroll
            for (int j = 0; j < 4; ++j)
                acc[i][j] = __builtin_amdgcn_mfma_f32_16x16x32_f16(
                    af[i], bf[j], acc[i][j], 0, 0, 0);
        __builtin_amdgcn_s_setprio(0);
        asm volatile("s_waitcnt vmcnt(3)" ::: "memory");  // slot h+1 landed
        __builtin_amdgcn_s_barrier();
    }

    const int col_l = lane & 15, row_l = (lane >> 4) * 4;
    #pragma unroll
    for (int i = 0; i < 4; ++i)
        #pragma unroll
        for (int j = 0; j < 4; ++j)
            #pragma unroll
            for (int r = 0; r < 4; ++r) {
                const int row = bm * 256 + wm + i * 16 + row_l + r;
                const int col = bn * 128 + wn + j * 16 + col_l;
                Cf[(size_t)row * N + col] = acc[i][j][r];
            }
}

// ---------------------------------------------------------------- host
extern "C" void kernel_launch(void* const* d_in, const int* in_sizes, int n_in,
                              void* d_out, int out_size, void* d_ws, size_t ws_size,
                              hipStream_t stream)
{
    const int*   tokens = (const int*)d_in[0];
    const float* emb  = (const float*)d_in[1];
    const float* g1   = (const float*)d_in[2];
    const float* Wqkv = (const float*)d_in[3];
    const float* Wa   = (const float*)d_in[4];
    const float* ba   = (const float*)d_in[5];
    const float* Wg   = (const float*)d_in[6];
    const float* Wo   = (const float*)d_in[7];
    const float* g2   = (const float*)d_in[8];
    const float* W1   = (const float*)d_in[9];
    const float* b1   = (const float*)d_in[10];
    const float* W2   = (const float*)d_in[11];
    const float* b2   = (const float*)d_in[12];
    const float* gf   = (const float*)d_in[13];
    const float* Wl   = (const float*)d_in[14];
    float* out = (float*)d_out;

    char* ws = (char*)d_ws;
    size_t off = 0;
    auto take = [&](size_t bytes) {
        char* p = ws + off; off += (bytes + 255) & ~(size_t)255; return p;
    };

    _Float16* wcat = (_Float16*)take((size_t)4 * 6144 * 1024 * 2);
    _Float16* wo   = (_Float16*)take((size_t)4 * 1024 * 1024 * 2);
    _Float16* w1   = (_Float16*)take((size_t)4 * 4096 * 1024 * 2);
    _Float16* w2   = (_Float16*)take((size_t)4 * 1024 * 4096 * 2);
    char*     wlRegion = take((size_t)64 << 20);
    _Float16* wl   = (_Float16*)wlRegion;
    float*    x    = (float*)take((size_t)4096 * 1024 * 4);
    _Float16* xn   = (_Float16*)take((size_t)4096 * 1024 * 2);
    float*    qkvb = (float*)take((size_t)4096 * 3072 * 4);
    float*    alb  = (float*)take((size_t)4096 * 2048 * 4);
    float*    G    = (float*)take((size_t)4096 * 1024 * 4);

    float* qT   = (float*)wlRegion;
    float* kvT  = (float*)(wlRegion + ((size_t)16 << 20));
    float* aReT = (float*)(wlRegion + ((size_t)32 << 20));
    float* aImT = (float*)(wlRegion + ((size_t)48 << 20));
    float*    yT    = alb;
    _Float16* gated = (_Float16*)((char*)alb + ((size_t)16 << 20));
    _Float16* h     = (_Float16*)qkvb;
    float*    part  = alb;

    const dim3 blk(256);

    transpose_f16_kernel<<<dim3(32,  96, 4), blk, 0, stream>>>(Wqkv, wcat,               1024, 3072, (size_t)6144 * 1024);
    transpose_f16_kernel<<<dim3(32,  64, 4), blk, 0, stream>>>(Wa,   wcat + 3072 * 1024, 1024, 2048, (size_t)6144 * 1024);
    transpose_f16_kernel<<<dim3(32,  32, 4), blk, 0, stream>>>(Wg,   wcat + 5120 * 1024, 1024, 1024, (size_t)6144 * 1024);
    transpose_f16_kernel<<<dim3(32,  32, 4), blk, 0, stream>>>(Wo,   wo,  1024, 1024, (size_t)1024 * 1024);
    transpose_f16_kernel<<<dim3(32, 128, 4), blk, 0, stream>>>(W1,   w1,  1024, 4096, (size_t)4096 * 1024);
    transpose_f16_kernel<<<dim3(128, 32, 4), blk, 0, stream>>>(W2,   w2,  4096, 1024, (size_t)1024 * 4096);

    embed_rms_kernel<<<4096, blk, 0, stream>>>(tokens, emb, g1, x, xn);

    for (int i = 0; i < 4; ++i) {
        gemm_kernel<6, 256, 128, 64><<<dim3(16, 48), dim3(512), 0, stream>>>(
            xn, wcat + (size_t)i * 6144 * 1024, ba + i * 2048,
            qkvb, alb, G, nullptr, 4096, 6144, 1024, 1024);
        prep_qkv_kernel<<<dim3(64, 32, 2), blk, 0, stream>>>(qkvb, qT, kvT);
        prep_a_kernel<<<dim3(64, 32, 2), blk, 0, stream>>>(alb, aReT, aImT);
        scanT_kernel<<<2048, blk, 0, stream>>>(kvT, aReT, aImT, qT, yT);
        gate_kernel<<<dim3(64, 32, 2), blk, 0, stream>>>(G, yT, gated);
        gemm_kernel<2, 128, 128, 64><<<dim3(32, 8), blk, 0, stream>>>(
            gated, wo + (size_t)i * 1024 * 1024, nullptr,
            x, nullptr, nullptr, nullptr, 4096, 1024, 1024, 1024);
        rms_f16_kernel<<<4096, blk, 0, stream>>>(x, g2 + i * 1024, xn);
        gemm_kernel<4, 256, 128, 64><<<dim3(16, 32), dim3(512), 0, stream>>>(
            xn, w1 + (size_t)i * 4096 * 1024, b1 + i * 4096,
            nullptr, nullptr, nullptr, h, 4096, 4096, 1024, 1024);
        gemm_kernel<0, 256, 128, 64><<<dim3(16, 8, 2), dim3(512), 0, stream>>>(
            h, w2 + (size_t)i * 1024 * 4096, nullptr,
            part, nullptr, nullptr, nullptr, 4096, 1024, 2048, 4096);
        const float* gnext = (i < 3) ? (g1 + (i + 1) * 1024) : gf;
        combine2_rms_kernel<<<4096, blk, 0, stream>>>(part, b2 + i * 1024, gnext, x, xn);
    }

    transpose_f16_kernel<<<dim3(32, 1000, 1), blk, 0, stream>>>(Wl, wl, 1024, 32000, 0);

    // logits: ring-3 counted-vmcnt pipeline (2 blocks/CU)
    gemm_ring3_kernel<<<dim3(16, 250), dim3(512), 0, stream>>>(
        xn, wl, out, 4096, 32000, 1024);
}

// Round 14
// 1562.958 us; speedup vs baseline: 1.1500x; 1.0590x over previous
//
#include <hip/hip_runtime.h>

// ---------------------------------------------------------------------------
// Transformer (GateLoop-style) forward, MI355X/gfx950.  Round 14.
//  = round 11 (all GEMMs on the proven 2-barrier 256x128/8-wave structure;
//    r12/r13 deep-pipeline attempts were nulls at K=1024 and are dropped)
//  + scan-prep FUSED into the qkv|a|g GEMM epilogue:
//      - wcat built with k,v column-interleaved (k[h]->1024+2h, v[h]->+1)
//        so lane l and l^1 hold (k,v) of the same head
//      - epilogue: q -> qT (fx4, transposed); k*v via shfl_xor(1) -> kvT;
//        a+bias -> polar via shfl_xor(1) -> aReT/aImT; g -> G row-major
//      - prep_qkv / prep_a kernels deleted (−2 launches, −144MB/layer)
//    Scan inputs bitwise-identical (same f32 values & op order).
// ---------------------------------------------------------------------------

typedef float fx4 __attribute__((ext_vector_type(4)));
typedef _Float16 f16x8 __attribute__((ext_vector_type(8)));
typedef _Float16 f16x4 __attribute__((ext_vector_type(4)));

#define AS1 __attribute__((address_space(1)))
#define AS3 __attribute__((address_space(3)))

// ---------------------------------------------------------------- transpose
__global__ __launch_bounds__(256) void transpose_f16_kernel(
    const float* __restrict__ in, _Float16* __restrict__ out,
    int K, int N, size_t ostride)
{
    __shared__ float tile[32][33];
    const int b = blockIdx.z;
    in  += (size_t)b * K * N;
    out += (size_t)b * ostride;
    const int k0 = blockIdx.x * 32, n0 = blockIdx.y * 32;
    const int tr = threadIdx.x >> 3;
    const int tc = (threadIdx.x & 7) * 4;
    fx4 v = *(const fx4*)&in[(size_t)(k0 + tr) * N + n0 + tc];
    tile[tr][tc + 0] = v[0]; tile[tr][tc + 1] = v[1];
    tile[tr][tc + 2] = v[2]; tile[tr][tc + 3] = v[3];
    __syncthreads();
    f16x4 o;
    #pragma unroll
    for (int e = 0; e < 4; ++e) o[e] = (_Float16)tile[tc + e][tr];
    *(f16x4*)&out[(size_t)(n0 + tr) * K + k0 + tc] = o;
}

// Wqkv transpose with k/v interleave: out_row(col) = col (col<1024),
// 1024+2*(col-1024) (k), 1024+2*(col-2048)+1 (v).  in f32[1024][3072].
__global__ __launch_bounds__(256) void transpose_qkv_kernel(
    const float* __restrict__ in, _Float16* __restrict__ out)
{
    __shared__ float tile[32][33];
    const int b = blockIdx.z;
    in  += (size_t)b * 1024 * 3072;
    out += (size_t)b * 6144 * 1024;
    const int k0 = blockIdx.x * 32, n0 = blockIdx.y * 32;
    const int tr = threadIdx.x >> 3;
    const int tc = (threadIdx.x & 7) * 4;
    fx4 v = *(const fx4*)&in[(size_t)(k0 + tr) * 3072 + n0 + tc];
    tile[tr][tc + 0] = v[0]; tile[tr][tc + 1] = v[1];
    tile[tr][tc + 2] = v[2]; tile[tr][tc + 3] = v[3];
    __syncthreads();
    const int col = n0 + tr;
    const int orow = (col < 1024) ? col
                   : (col < 2048) ? 1024 + 2 * (col - 1024)
                                  : 1024 + 2 * (col - 2048) + 1;
    f16x4 o;
    #pragma unroll
    for (int e = 0; e < 4; ++e) o[e] = (_Float16)tile[tc + e][tr];
    *(f16x4*)&out[(size_t)orow * 1024 + k0 + tc] = o;
}

// ---------------------------------------------------------------- row RMS helper
__device__ __forceinline__ float row_rms_scale(float ss) {
    #pragma unroll
    for (int off = 32; off > 0; off >>= 1) ss += __shfl_down(ss, off, 64);
    __shared__ float wsum[4];
    if ((threadIdx.x & 63) == 0) wsum[threadIdx.x >> 6] = ss;
    __syncthreads();
    const float nrm = sqrtf(wsum[0] + wsum[1] + wsum[2] + wsum[3]);
    return 32.0f / fmaxf(nrm, 1e-12f);
}

// ---------------------------------------------------------------- embed + rms
__global__ __launch_bounds__(256) void embed_rms_kernel(
    const int* __restrict__ tokens, const float* __restrict__ emb,
    const float* __restrict__ g, float* __restrict__ x, _Float16* __restrict__ xn)
{
    const int row = blockIdx.x;
    const int t = tokens[row];
    const int c = threadIdx.x * 4;
    fx4 v = *(const fx4*)&emb[(size_t)t * 1024 + c];
    *(fx4*)&x[(size_t)row * 1024 + c] = v;
    const float scale = row_rms_scale(v[0]*v[0] + v[1]*v[1] + v[2]*v[2] + v[3]*v[3]);
    fx4 gg = *(const fx4*)&g[c];
    f16x4 o;
    #pragma unroll
    for (int e = 0; e < 4; ++e) o[e] = (_Float16)(v[e] * scale * gg[e]);
    *(f16x4*)&xn[(size_t)row * 1024 + c] = o;
}

// ---------------------------------------------------------------- rms -> fp16
__global__ __launch_bounds__(256) void rms_f16_kernel(
    const float* __restrict__ x, const float* __restrict__ g,
    _Float16* __restrict__ outh)
{
    const int row = blockIdx.x;
    const int c = threadIdx.x * 4;
    fx4 v = *(const fx4*)&x[(size_t)row * 1024 + c];
    const float scale = row_rms_scale(v[0]*v[0] + v[1]*v[1] + v[2]*v[2] + v[3]*v[3]);
    fx4 gg = *(const fx4*)&g[c];
    f16x4 o;
    #pragma unroll
    for (int e = 0; e < 4; ++e) o[e] = (_Float16)(v[e] * scale * gg[e]);
    *(f16x4*)&outh[(size_t)row * 1024 + c] = o;
}

// ---------------------------------------------------------------- gate-loop scan
__device__ __forceinline__ int pidx(int i) { return i + (i >> 5); }

__global__ __launch_bounds__(256) void scanT_kernel(
    const float* __restrict__ kvT, const float* __restrict__ aReT,
    const float* __restrict__ aImT, const float* __restrict__ qT,
    float* __restrict__ yT)
{
    const int tid = threadIdx.x;
    const size_t base = (size_t)blockIdx.x * 2048;
    __shared__ float s_re[2048 + 64], s_im[2048 + 64], s_kv[2048 + 64];

    for (int i = tid; i < 512; i += 256) {
        fx4 kv = *(const fx4*)&kvT[base + i * 4];
        fx4 re = *(const fx4*)&aReT[base + i * 4];
        fx4 im = *(const fx4*)&aImT[base + i * 4];
        #pragma unroll
        for (int e = 0; e < 4; ++e) {
            const int j = pidx(i * 4 + e);
            s_kv[j] = kv[e]; s_re[j] = re[e]; s_im[j] = im[e];
        }
    }
    __syncthreads();

    for (int d = 0; d < 11; ++d) {
        const int half = 1 << d, stride = half << 1;
        const int npairs = 2048 >> (d + 1);
        for (int i = tid; i < npairs; i += 256) {
            const int rj = pidx(i * stride + stride - 1);
            const int lj = pidx(i * stride + stride - 1 - half);
            float lre = s_re[lj], lim = s_im[lj], lkv = s_kv[lj];
            float rre = s_re[rj], rim = s_im[rj], rkv = s_kv[rj];
            s_kv[rj] = rre * lkv + rkv;
            s_re[rj] = rre * lre - rim * lim;
            s_im[rj] = rre * lim + rim * lre;
        }
        __syncthreads();
    }
    for (int d = 9; d >= 0; --d) {
        const int w = 1 << d;
        const int nupd = (2048 >> (d + 1)) - 1;
        for (int t = tid; t < nupd; t += 256) {
            const int i = t + 1;
            const int rj = pidx((2 * i + 1) * w - 1);
            const int lj = pidx(2 * i * w - 1);
            float lre = s_re[lj], lim = s_im[lj], lkv = s_kv[lj];
            float rre = s_re[rj], rim = s_im[rj], rkv = s_kv[rj];
            s_kv[rj] = rre * lkv + rkv;
            s_re[rj] = rre * lre - rim * lim;
            s_im[rj] = rre * lim + rim * lre;
        }
        __syncthreads();
    }
    for (int i = tid; i < 512; i += 256) {
        fx4 q = *(const fx4*)&qT[base + i * 4];
        fx4 o;
        #pragma unroll
        for (int e = 0; e < 4; ++e) o[e] = q[e] * s_kv[pidx(i * 4 + e)];
        *(fx4*)&yT[base + i * 4] = o;
    }
}

// ---------------------------------------------------------------- gating
__global__ __launch_bounds__(256) void gate_kernel(
    const float* __restrict__ G, const float* __restrict__ yT,
    _Float16* __restrict__ gated)
{
    __shared__ float ty[32][33];
    const int n0 = blockIdx.x * 32, h0 = blockIdx.y * 32, b = blockIdx.z;
    const int tr = threadIdx.x >> 3;
    const int tc = (threadIdx.x & 7) * 4;
    fx4 yv = *(const fx4*)&yT[((size_t)b * 1024 + h0 + tr) * 2048 + n0 + tc];
    #pragma unroll
    for (int e = 0; e < 4; ++e) ty[tr][tc + e] = yv[e];
    __syncthreads();
    const size_t grow = ((size_t)b * 2048 + n0 + tr) * 1024 + h0 + tc;
    fx4 gv = *(const fx4*)&G[grow];
    f16x4 o;
    #pragma unroll
    for (int e = 0; e < 4; ++e) {
        const float s = gv[e] / (1.0f + expf(-gv[e]));   // silu
        o[e] = (_Float16)(s * ty[tc + e][tr]);
    }
    *(f16x4*)&gated[grow] = o;
}

// ---------------------------------------------------------------- W2 combine + next-layer RMS
__global__ __launch_bounds__(256) void combine2_rms_kernel(
    const float* __restrict__ p, const float* __restrict__ bias,
    const float* __restrict__ g, float* __restrict__ x, _Float16* __restrict__ xn)
{
    const int row = blockIdx.x;
    const int c = threadIdx.x * 4;
    const size_t i = (size_t)row * 1024 + c;
    fx4 a = *(const fx4*)&p[i];
    fx4 b = *(const fx4*)&p[i + (size_t)4096 * 1024];
    fx4 xx = *(const fx4*)&x[i];
    fx4 bb = *(const fx4*)&bias[c];
    fx4 o;
    #pragma unroll
    for (int e = 0; e < 4; ++e) o[e] = xx[e] + (a[e] + b[e] + bb[e]);
    *(fx4*)&x[i] = o;
    const float scale = row_rms_scale(o[0]*o[0] + o[1]*o[1] + o[2]*o[2] + o[3]*o[3]);
    fx4 gg = *(const fx4*)&g[c];
    f16x4 oh;
    #pragma unroll
    for (int e = 0; e < 4; ++e) oh[e] = (_Float16)(o[e] * scale * gg[e]);
    *(f16x4*)&xn[i] = oh;
}

// ---------------------------------------------------------------- GEMM (2-barrier, proven)
// EPI: 0=store f32 (+bz*M*N), 2=Cf+=v, 4=Ch=f16(gelu(v+bias)),
//      6=fused scan-prep routing (N=6144, k/v-interleaved wcat):
//        col<1024:  q  -> Cf  = qT  [(b*1024+col)*2048+n]  (fx4)
//        col<3072:  kv -> Cf2 = kvT [(b*1024+h)*2048+n]    (even lanes, fx4)
//        col<5120:  a+bias -> polar -> aRe/aIm [(b*1024+h)*2048+n]
//        else:      g  -> Cf3 = G row-major [row*1024 + col-5120]
template<int EPI, int BM, int BN, int WTM>
__global__ __launch_bounds__((BM / WTM) * (BN / 64) * 64) void gemm_kernel(
    const _Float16* __restrict__ A, const _Float16* __restrict__ Bt,
    const float* __restrict__ bias,
    float* __restrict__ Cf, float* __restrict__ Cf2, float* __restrict__ Cf3,
    float* __restrict__ aRe, float* __restrict__ aIm,
    _Float16* __restrict__ Ch,
    int M, int N, int K, int Kld)
{
    constexpr int NW      = BN / 64;
    constexpr int THREADS = (BM / WTM) * NW * 64;
    constexpr int M_REP   = WTM / 16;
    __shared__ __align__(16) _Float16 As[BM * 64];
    __shared__ __align__(16) _Float16 Bs[BN * 64];
    const int tid  = threadIdx.x;
    const int lane = tid & 63;
    const int wave = tid >> 6;
    const int bm = blockIdx.x, bn = blockIdx.y;
    const int bz = blockIdx.z;
    const int wm = (wave / NW) * WTM;
    const int wn = (wave % NW) * 64;

    A  += (size_t)bz * K;
    Bt += (size_t)bz * K;
    if (EPI == 0) Cf += (size_t)bz * M * N;

    fx4 acc[M_REP][4] = {};

    const size_t aRow0 = (size_t)bm * BM;
    const size_t bRow0 = (size_t)bn * BN;

    for (int k0 = 0; k0 < K; k0 += 64) {
        constexpr int QA = BM * 8 / THREADS;
        #pragma unroll
        for (int q = 0; q < QA; ++q) {
            const int chunk = q * THREADS + tid;
            const int row = chunk >> 3;
            const int slot = chunk & 7;
            const int gs = slot ^ (row & 7);
            const size_t aoff = (aRow0 + row) * (size_t)Kld + k0 + gs * 8;
            __builtin_amdgcn_global_load_lds((const AS1 void*)(A + aoff),
                (AS3 void*)((char*)As + chunk * 16), 16, 0, 0);
        }
        constexpr int QB = BN * 8 / THREADS;
        #pragma unroll
        for (int q = 0; q < QB; ++q) {
            const int chunk = q * THREADS + tid;
            const int row = chunk >> 3;
            const int slot = chunk & 7;
            const int gs = slot ^ (row & 7);
            const size_t boff = (bRow0 + row) * (size_t)Kld + k0 + gs * 8;
            __builtin_amdgcn_global_load_lds((const AS1 void*)(Bt + boff),
                (AS3 void*)((char*)Bs + chunk * 16), 16, 0, 0);
        }
        __syncthreads();

        #pragma unroll
        for (int kk = 0; kk < 2; ++kk) {
            const int sw = ((kk * 4 + (lane >> 4)) ^ (lane & 7)) * 16;
            f16x8 af[M_REP], bf[4];
            #pragma unroll
            for (int i = 0; i < M_REP; ++i) {
                const int row = wm + i * 16 + (lane & 15);
                af[i] = *(const f16x8*)((const char*)As + row * 128 + sw);
            }
            #pragma unroll
            for (int j = 0; j < 4; ++j) {
                const int row = wn + j * 16 + (lane & 15);
                bf[j] = *(const f16x8*)((const char*)Bs + row * 128 + sw);
            }
            #pragma unroll
            for (int i = 0; i < M_REP; ++i)
                #pragma unroll
                for (int j = 0; j < 4; ++j)
                    acc[i][j] = __builtin_amdgcn_mfma_f32_16x16x32_f16(
                        af[i], bf[j], acc[i][j], 0, 0, 0);
        }
        __syncthreads();
    }

    // epilogue: C/D layout col=lane&15, row=(lane>>4)*4+r
    const int col_l = lane & 15, row_l = (lane >> 4) * 4;
    #pragma unroll
    for (int i = 0; i < M_REP; ++i) {
        #pragma unroll
        for (int j = 0; j < 4; ++j) {
            if (EPI == 6) {
                const int col  = bn * BN + wn + j * 16 + col_l;
                const int row0 = bm * BM + wm + i * 16 + row_l;  // 4 consecutive
                const int b = row0 >> 11;
                const int n = row0 & 2047;
                if (col < 1024) {
                    *(fx4*)&Cf[((size_t)b * 1024 + col) * 2048 + n] = acc[i][j];
                } else if (col < 3072) {
                    // even col = k(h), odd = v(h); h = (col-1024)>>1
                    fx4 partner;
                    #pragma unroll
                    for (int e = 0; e < 4; ++e)
                        partner[e] = __shfl_xor(acc[i][j][e], 1, 64);
                    if ((col & 1) == 0) {
                        fx4 kv;
                        #pragma unroll
                        for (int e = 0; e < 4; ++e) kv[e] = acc[i][j][e] * partner[e];
                        const int hh = (col - 1024) >> 1;
                        *(fx4*)&Cf2[((size_t)b * 1024 + hh) * 2048 + n] = kv;
                    }
                } else if (col < 5120) {
                    fx4 my;
                    #pragma unroll
                    for (int e = 0; e < 4; ++e) my[e] = acc[i][j][e] + bias[col - 3072];
                    fx4 partner;
                    #pragma unroll
                    for (int e = 0; e < 4; ++e)
                        partner[e] = __shfl_xor(my[e], 1, 64);
                    const bool isRe = (col & 1) == 0;
                    const int hh = (col - 3072) >> 1;
                    fx4 o;
                    #pragma unroll
                    for (int e = 0; e < 4; ++e) {
                        const float re = isRe ? my[e] : partner[e];
                        const float im = isRe ? partner[e] : my[e];
                        const float r = sqrtf(re * re + im * im);
                        const float sg = 1.0f / (1.0f + expf(-r));
                        float a_re, a_im;
                        if (r > 0.0f) { const float inv = sg / r; a_re = re * inv; a_im = im * inv; }
                        else          { a_re = sg; a_im = 0.0f; }
                        o[e] = isRe ? a_re : a_im;
                    }
                    if (isRe) *(fx4*)&aRe[((size_t)b * 1024 + hh) * 2048 + n] = o;
                    else      *(fx4*)&aIm[((size_t)b * 1024 + hh) * 2048 + n] = o;
                } else {
                    #pragma unroll
                    for (int r = 0; r < 4; ++r)
                        Cf3[(size_t)(row0 + r) * 1024 + (col - 5120)] = acc[i][j][r];
                }
            } else {
                #pragma unroll
                for (int r = 0; r < 4; ++r) {
                    const int row = bm * BM + wm + i * 16 + row_l + r;
                    const int col = bn * BN + wn + j * 16 + col_l;
                    const float v = acc[i][j][r];
                    if (EPI == 0) {
                        Cf[(size_t)row * N + col] = v;
                    } else if (EPI == 2) {
                        Cf[(size_t)row * N + col] += v;
                    } else if (EPI == 4) {
                        const float t = v + bias[col];
                        const float gelu = 0.5f * t * (1.0f + erff(t * 0.70710678118654752f));
                        Ch[(size_t)row * N + col] = (_Float16)gelu;
                    }
                }
            }
        }
    }
}

// ---------------------------------------------------------------- host
extern "C" void kernel_launch(void* const* d_in, const int* in_sizes, int n_in,
                              void* d_out, int out_size, void* d_ws, size_t ws_size,
                              hipStream_t stream)
{
    const int*   tokens = (const int*)d_in[0];
    const float* emb  = (const float*)d_in[1];
    const float* g1   = (const float*)d_in[2];
    const float* Wqkv = (const float*)d_in[3];
    const float* Wa   = (const float*)d_in[4];
    const float* ba   = (const float*)d_in[5];
    const float* Wg   = (const float*)d_in[6];
    const float* Wo   = (const float*)d_in[7];
    const float* g2   = (const float*)d_in[8];
    const float* W1   = (const float*)d_in[9];
    const float* b1   = (const float*)d_in[10];
    const float* W2   = (const float*)d_in[11];
    const float* b2   = (const float*)d_in[12];
    const float* gf   = (const float*)d_in[13];
    const float* Wl   = (const float*)d_in[14];
    float* out = (float*)d_out;

    char* ws = (char*)d_ws;
    size_t off = 0;
    auto take = [&](size_t bytes) {
        char* p = ws + off; off += (bytes + 255) & ~(size_t)255; return p;
    };

    _Float16* wcat = (_Float16*)take((size_t)4 * 6144 * 1024 * 2);
    _Float16* wo   = (_Float16*)take((size_t)4 * 1024 * 1024 * 2);
    _Float16* w1   = (_Float16*)take((size_t)4 * 4096 * 1024 * 2);
    _Float16* w2   = (_Float16*)take((size_t)4 * 1024 * 4096 * 2);
    char*     wlRegion = take((size_t)64 << 20);
    _Float16* wl   = (_Float16*)wlRegion;
    float*    x    = (float*)take((size_t)4096 * 1024 * 4);
    _Float16* xn   = (_Float16*)take((size_t)4096 * 1024 * 2);
    float*    qkvb = (float*)take((size_t)4096 * 3072 * 4);   // now: h (W1 out) only
    float*    alb  = (float*)take((size_t)4096 * 2048 * 4);   // yT / gated / W2 partials
    float*    G    = (float*)take((size_t)4096 * 1024 * 4);

    float* qT   = (float*)wlRegion;
    float* kvT  = (float*)(wlRegion + ((size_t)16 << 20));
    float* aReT = (float*)(wlRegion + ((size_t)32 << 20));
    float* aImT = (float*)(wlRegion + ((size_t)48 << 20));
    float*    yT    = alb;
    _Float16* gated = (_Float16*)((char*)alb + ((size_t)16 << 20));
    _Float16* h     = (_Float16*)qkvb;
    float*    part  = alb;

    const dim3 blk(256);

    transpose_qkv_kernel<<<dim3(32, 96, 4), blk, 0, stream>>>(Wqkv, wcat);
    transpose_f16_kernel<<<dim3(32,  64, 4), blk, 0, stream>>>(Wa,   wcat + 3072 * 1024, 1024, 2048, (size_t)6144 * 1024);
    transpose_f16_kernel<<<dim3(32,  32, 4), blk, 0, stream>>>(Wg,   wcat + 5120 * 1024, 1024, 1024, (size_t)6144 * 1024);
    transpose_f16_kernel<<<dim3(32,  32, 4), blk, 0, stream>>>(Wo,   wo,  1024, 1024, (size_t)1024 * 1024);
    transpose_f16_kernel<<<dim3(32, 128, 4), blk, 0, stream>>>(W1,   w1,  1024, 4096, (size_t)4096 * 1024);
    transpose_f16_kernel<<<dim3(128, 32, 4), blk, 0, stream>>>(W2,   w2,  4096, 1024, (size_t)1024 * 4096);

    embed_rms_kernel<<<4096, blk, 0, stream>>>(tokens, emb, g1, x, xn);

    for (int i = 0; i < 4; ++i) {
        // fused qkv|a|g GEMM with scan-prep epilogue
        gemm_kernel<6, 256, 128, 64><<<dim3(16, 48), dim3(512), 0, stream>>>(
            xn, wcat + (size_t)i * 6144 * 1024, ba + i * 2048,
            qT, kvT, G, aReT, aImT, nullptr, 4096, 6144, 1024, 1024);
        scanT_kernel<<<2048, blk, 0, stream>>>(kvT, aReT, aImT, qT, yT);
        gate_kernel<<<dim3(64, 32, 2), blk, 0, stream>>>(G, yT, gated);
        gemm_kernel<2, 128, 128, 64><<<dim3(32, 8), blk, 0, stream>>>(
            gated, wo + (size_t)i * 1024 * 1024, nullptr,
            x, nullptr, nullptr, nullptr, nullptr, nullptr, 4096, 1024, 1024, 1024);
        rms_f16_kernel<<<4096, blk, 0, stream>>>(x, g2 + i * 1024, xn);
        gemm_kernel<4, 256, 128, 64><<<dim3(16, 32), dim3(512), 0, stream>>>(
            xn, w1 + (size_t)i * 4096 * 1024, b1 + i * 4096,
            nullptr, nullptr, nullptr, nullptr, nullptr, h, 4096, 4096, 1024, 1024);
        gemm_kernel<0, 256, 128, 64><<<dim3(16, 8, 2), dim3(512), 0, stream>>>(
            h, w2 + (size_t)i * 1024 * 4096, nullptr,
            part, nullptr, nullptr, nullptr, nullptr, nullptr, 4096, 1024, 2048, 4096);
        const float* gnext = (i < 3) ? (g1 + (i + 1) * 1024) : gf;
        combine2_rms_kernel<<<4096, blk, 0, stream>>>(part, b2 + i * 1024, gnext, x, xn);
    }

    transpose_f16_kernel<<<dim3(32, 1000, 1), blk, 0, stream>>>(Wl, wl, 1024, 32000, 0);

    // logits: proven 2-barrier kernel (r11: ~315us)
    gemm_kernel<0, 256, 128, 64><<<dim3(16, 250), dim3(512), 0, stream>>>(
        xn, wl, nullptr, out, nullptr, nullptr, nullptr, nullptr, nullptr,
        4096, 32000, 1024, 1024);
}

// Round 15
// 1546.115 us; speedup vs baseline: 1.1625x; 1.0109x over previous
//
#include <hip/hip_runtime.h>

// ---------------------------------------------------------------------------
// Transformer (GateLoop-style) forward, MI355X/gfx950.  Round 15.
//  = round 14 +
//   (1) barrier-trimmed Brent-Kung scan: levels with <=64 active pairs
//       (up d=4..10, down d=9..4) run wave-synchronously in wave 0 only
//       -> 21 barriers/block -> 9.  Same ops, same bracketing, same indices.
//   (2) gate pre-activations G stored fp16 (fused epilogue writes f16 via Ch;
//       gate kernel reads f16) -> -16 MB/layer traffic.
//  GEMMs unchanged (2-barrier 256x128/8-wave structure; r12/r13 deep-pipeline
//  attempts were nulls at K=1024 and stay dropped).
// ---------------------------------------------------------------------------

typedef float fx4 __attribute__((ext_vector_type(4)));
typedef _Float16 f16x8 __attribute__((ext_vector_type(8)));
typedef _Float16 f16x4 __attribute__((ext_vector_type(4)));

#define AS1 __attribute__((address_space(1)))
#define AS3 __attribute__((address_space(3)))

// ---------------------------------------------------------------- transpose
__global__ __launch_bounds__(256) void transpose_f16_kernel(
    const float* __restrict__ in, _Float16* __restrict__ out,
    int K, int N, size_t ostride)
{
    __shared__ float tile[32][33];
    const int b = blockIdx.z;
    in  += (size_t)b * K * N;
    out += (size_t)b * ostride;
    const int k0 = blockIdx.x * 32, n0 = blockIdx.y * 32;
    const int tr = threadIdx.x >> 3;
    const int tc = (threadIdx.x & 7) * 4;
    fx4 v = *(const fx4*)&in[(size_t)(k0 + tr) * N + n0 + tc];
    tile[tr][tc + 0] = v[0]; tile[tr][tc + 1] = v[1];
    tile[tr][tc + 2] = v[2]; tile[tr][tc + 3] = v[3];
    __syncthreads();
    f16x4 o;
    #pragma unroll
    for (int e = 0; e < 4; ++e) o[e] = (_Float16)tile[tc + e][tr];
    *(f16x4*)&out[(size_t)(n0 + tr) * K + k0 + tc] = o;
}

// Wqkv transpose with k/v interleave: out_row(col) = col (col<1024),
// 1024+2*(col-1024) (k), 1024+2*(col-2048)+1 (v).  in f32[1024][3072].
__global__ __launch_bounds__(256) void transpose_qkv_kernel(
    const float* __restrict__ in, _Float16* __restrict__ out)
{
    __shared__ float tile[32][33];
    const int b = blockIdx.z;
    in  += (size_t)b * 1024 * 3072;
    out += (size_t)b * 6144 * 1024;
    const int k0 = blockIdx.x * 32, n0 = blockIdx.y * 32;
    const int tr = threadIdx.x >> 3;
    const int tc = (threadIdx.x & 7) * 4;
    fx4 v = *(const fx4*)&in[(size_t)(k0 + tr) * 3072 + n0 + tc];
    tile[tr][tc + 0] = v[0]; tile[tr][tc + 1] = v[1];
    tile[tr][tc + 2] = v[2]; tile[tr][tc + 3] = v[3];
    __syncthreads();
    const int col = n0 + tr;
    const int orow = (col < 1024) ? col
                   : (col < 2048) ? 1024 + 2 * (col - 1024)
                                  : 1024 + 2 * (col - 2048) + 1;
    f16x4 o;
    #pragma unroll
    for (int e = 0; e < 4; ++e) o[e] = (_Float16)tile[tc + e][tr];
    *(f16x4*)&out[(size_t)orow * 1024 + k0 + tc] = o;
}

// ---------------------------------------------------------------- row RMS helper
__device__ __forceinline__ float row_rms_scale(float ss) {
    #pragma unroll
    for (int off = 32; off > 0; off >>= 1) ss += __shfl_down(ss, off, 64);
    __shared__ float wsum[4];
    if ((threadIdx.x & 63) == 0) wsum[threadIdx.x >> 6] = ss;
    __syncthreads();
    const float nrm = sqrtf(wsum[0] + wsum[1] + wsum[2] + wsum[3]);
    return 32.0f / fmaxf(nrm, 1e-12f);
}

// ---------------------------------------------------------------- embed + rms
__global__ __launch_bounds__(256) void embed_rms_kernel(
    const int* __restrict__ tokens, const float* __restrict__ emb,
    const float* __restrict__ g, float* __restrict__ x, _Float16* __restrict__ xn)
{
    const int row = blockIdx.x;
    const int t = tokens[row];
    const int c = threadIdx.x * 4;
    fx4 v = *(const fx4*)&emb[(size_t)t * 1024 + c];
    *(fx4*)&x[(size_t)row * 1024 + c] = v;
    const float scale = row_rms_scale(v[0]*v[0] + v[1]*v[1] + v[2]*v[2] + v[3]*v[3]);
    fx4 gg = *(const fx4*)&g[c];
    f16x4 o;
    #pragma unroll
    for (int e = 0; e < 4; ++e) o[e] = (_Float16)(v[e] * scale * gg[e]);
    *(f16x4*)&xn[(size_t)row * 1024 + c] = o;
}

// ---------------------------------------------------------------- rms -> fp16
__global__ __launch_bounds__(256) void rms_f16_kernel(
    const float* __restrict__ x, const float* __restrict__ g,
    _Float16* __restrict__ outh)
{
    const int row = blockIdx.x;
    const int c = threadIdx.x * 4;
    fx4 v = *(const fx4*)&x[(size_t)row * 1024 + c];
    const float scale = row_rms_scale(v[0]*v[0] + v[1]*v[1] + v[2]*v[2] + v[3]*v[3]);
    fx4 gg = *(const fx4*)&g[c];
    f16x4 o;
    #pragma unroll
    for (int e = 0; e < 4; ++e) o[e] = (_Float16)(v[e] * scale * gg[e]);
    *(f16x4*)&outh[(size_t)row * 1024 + c] = o;
}

// ---------------------------------------------------------------- gate-loop scan
// Brent-Kung == jax.lax.associative_scan bracketing (binop NON-associative).
// Levels with <=64 active pairs run wave-synchronously in wave 0 (no barrier;
// compiler-inserted lgkmcnt orders the LDS deps within the wave).
__device__ __forceinline__ int pidx(int i) { return i + (i >> 5); }

__global__ __launch_bounds__(256) void scanT_kernel(
    const float* __restrict__ kvT, const float* __restrict__ aReT,
    const float* __restrict__ aImT, const float* __restrict__ qT,
    float* __restrict__ yT)
{
    const int tid = threadIdx.x;
    const size_t base = (size_t)blockIdx.x * 2048;
    __shared__ float s_re[2048 + 64], s_im[2048 + 64], s_kv[2048 + 64];

    for (int i = tid; i < 512; i += 256) {
        fx4 kv = *(const fx4*)&kvT[base + i * 4];
        fx4 re = *(const fx4*)&aReT[base + i * 4];
        fx4 im = *(const fx4*)&aImT[base + i * 4];
        #pragma unroll
        for (int e = 0; e < 4; ++e) {
            const int j = pidx(i * 4 + e);
            s_kv[j] = kv[e]; s_re[j] = re[e]; s_im[j] = im[e];
        }
    }
    __syncthreads();

    // up-sweep, all-thread levels (npairs >= 128)
    for (int d = 0; d < 4; ++d) {
        const int half = 1 << d, stride = half << 1;
        const int npairs = 2048 >> (d + 1);
        for (int i = tid; i < npairs; i += 256) {
            const int rj = pidx(i * stride + stride - 1);
            const int lj = pidx(i * stride + stride - 1 - half);
            float lre = s_re[lj], lim = s_im[lj], lkv = s_kv[lj];
            float rre = s_re[rj], rim = s_im[rj], rkv = s_kv[rj];
            s_kv[rj] = rre * lkv + rkv;
            s_re[rj] = rre * lre - rim * lim;
            s_im[rj] = rre * lim + rim * lre;
        }
        __syncthreads();
    }
    // wave-synchronous middle: up d=4..10, down d=9..4 (<=64 active each)
    if (tid < 64) {
        #pragma unroll
        for (int d = 4; d < 11; ++d) {
            const int half = 1 << d, stride = half << 1;
            const int npairs = 2048 >> (d + 1);
            if (tid < npairs) {
                const int rj = pidx(tid * stride + stride - 1);
                const int lj = pidx(tid * stride + stride - 1 - half);
                float lre = s_re[lj], lim = s_im[lj], lkv = s_kv[lj];
                float rre = s_re[rj], rim = s_im[rj], rkv = s_kv[rj];
                s_kv[rj] = rre * lkv + rkv;
                s_re[rj] = rre * lre - rim * lim;
                s_im[rj] = rre * lim + rim * lre;
            }
        }
        #pragma unroll
        for (int d = 9; d >= 4; --d) {
            const int w = 1 << d;
            const int nupd = (2048 >> (d + 1)) - 1;
            if (tid < nupd) {
                const int i = tid + 1;
                const int rj = pidx((2 * i + 1) * w - 1);
                const int lj = pidx(2 * i * w - 1);
                float lre = s_re[lj], lim = s_im[lj], lkv = s_kv[lj];
                float rre = s_re[rj], rim = s_im[rj], rkv = s_kv[rj];
                s_kv[rj] = rre * lkv + rkv;
                s_re[rj] = rre * lre - rim * lim;
                s_im[rj] = rre * lim + rim * lre;
            }
        }
    }
    __syncthreads();
    // down-sweep, all-thread levels (nupd >= 127)
    for (int d = 3; d >= 0; --d) {
        const int w = 1 << d;
        const int nupd = (2048 >> (d + 1)) - 1;
        for (int t = tid; t < nupd; t += 256) {
            const int i = t + 1;
            const int rj = pidx((2 * i + 1) * w - 1);
            const int lj = pidx(2 * i * w - 1);
            float lre = s_re[lj], lim = s_im[lj], lkv = s_kv[lj];
            float rre = s_re[rj], rim = s_im[rj], rkv = s_kv[rj];
            s_kv[rj] = rre * lkv + rkv;
            s_re[rj] = rre * lre - rim * lim;
            s_im[rj] = rre * lim + rim * lre;
        }
        __syncthreads();
    }
    for (int i = tid; i < 512; i += 256) {
        fx4 q = *(const fx4*)&qT[base + i * 4];
        fx4 o;
        #pragma unroll
        for (int e = 0; e < 4; ++e) o[e] = q[e] * s_kv[pidx(i * 4 + e)];
        *(fx4*)&yT[base + i * 4] = o;
    }
}

// ---------------------------------------------------------------- gating
__global__ __launch_bounds__(256) void gate_kernel(
    const _Float16* __restrict__ G, const float* __restrict__ yT,
    _Float16* __restrict__ gated)
{
    __shared__ float ty[32][33];
    const int n0 = blockIdx.x * 32, h0 = blockIdx.y * 32, b = blockIdx.z;
    const int tr = threadIdx.x >> 3;
    const int tc = (threadIdx.x & 7) * 4;
    fx4 yv = *(const fx4*)&yT[((size_t)b * 1024 + h0 + tr) * 2048 + n0 + tc];
    #pragma unroll
    for (int e = 0; e < 4; ++e) ty[tr][tc + e] = yv[e];
    __syncthreads();
    const size_t grow = ((size_t)b * 2048 + n0 + tr) * 1024 + h0 + tc;
    f16x4 gv = *(const f16x4*)&G[grow];
    f16x4 o;
    #pragma unroll
    for (int e = 0; e < 4; ++e) {
        const float g = (float)gv[e];
        const float s = g / (1.0f + expf(-g));   // silu
        o[e] = (_Float16)(s * ty[tc + e][tr]);
    }
    *(f16x4*)&gated[grow] = o;
}

// ---------------------------------------------------------------- W2 combine + next-layer RMS
__global__ __launch_bounds__(256) void combine2_rms_kernel(
    const float* __restrict__ p, const float* __restrict__ bias,
    const float* __restrict__ g, float* __restrict__ x, _Float16* __restrict__ xn)
{
    const int row = blockIdx.x;
    const int c = threadIdx.x * 4;
    const size_t i = (size_t)row * 1024 + c;
    fx4 a = *(const fx4*)&p[i];
    fx4 b = *(const fx4*)&p[i + (size_t)4096 * 1024];
    fx4 xx = *(const fx4*)&x[i];
    fx4 bb = *(const fx4*)&bias[c];
    fx4 o;
    #pragma unroll
    for (int e = 0; e < 4; ++e) o[e] = xx[e] + (a[e] + b[e] + bb[e]);
    *(fx4*)&x[i] = o;
    const float scale = row_rms_scale(o[0]*o[0] + o[1]*o[1] + o[2]*o[2] + o[3]*o[3]);
    fx4 gg = *(const fx4*)&g[c];
    f16x4 oh;
    #pragma unroll
    for (int e = 0; e < 4; ++e) oh[e] = (_Float16)(o[e] * scale * gg[e]);
    *(f16x4*)&xn[i] = oh;
}

// ---------------------------------------------------------------- GEMM (2-barrier, proven)
// EPI: 0=store f32 (+bz*M*N), 2=Cf+=v, 4=Ch=f16(gelu(v+bias)),
//      6=fused scan-prep routing (N=6144, k/v-interleaved wcat):
//        col<1024:  q  -> Cf  = qT  [(b*1024+col)*2048+n]  (fx4)
//        col<3072:  kv -> Cf2 = kvT [(b*1024+h)*2048+n]    (even lanes, fx4)
//        col<5120:  a+bias -> polar -> aRe/aIm [(b*1024+h)*2048+n]
//        else:      g  -> Ch (f16) row-major [row*1024 + col-5120]
template<int EPI, int BM, int BN, int WTM>
__global__ __launch_bounds__((BM / WTM) * (BN / 64) * 64) void gemm_kernel(
    const _Float16* __restrict__ A, const _Float16* __restrict__ Bt,
    const float* __restrict__ bias,
    float* __restrict__ Cf, float* __restrict__ Cf2, float* __restrict__ Cf3,
    float* __restrict__ aRe, float* __restrict__ aIm,
    _Float16* __restrict__ Ch,
    int M, int N, int K, int Kld)
{
    constexpr int NW      = BN / 64;
    constexpr int THREADS = (BM / WTM) * NW * 64;
    constexpr int M_REP   = WTM / 16;
    __shared__ __align__(16) _Float16 As[BM * 64];
    __shared__ __align__(16) _Float16 Bs[BN * 64];
    const int tid  = threadIdx.x;
    const int lane = tid & 63;
    const int wave = tid >> 6;
    const int bm = blockIdx.x, bn = blockIdx.y;
    const int bz = blockIdx.z;
    const int wm = (wave / NW) * WTM;
    const int wn = (wave % NW) * 64;

    A  += (size_t)bz * K;
    Bt += (size_t)bz * K;
    if (EPI == 0) Cf += (size_t)bz * M * N;

    fx4 acc[M_REP][4] = {};

    const size_t aRow0 = (size_t)bm * BM;
    const size_t bRow0 = (size_t)bn * BN;

    for (int k0 = 0; k0 < K; k0 += 64) {
        constexpr int QA = BM * 8 / THREADS;
        #pragma unroll
        for (int q = 0; q < QA; ++q) {
            const int chunk = q * THREADS + tid;
            const int row = chunk >> 3;
            const int slot = chunk & 7;
            const int gs = slot ^ (row & 7);
            const size_t aoff = (aRow0 + row) * (size_t)Kld + k0 + gs * 8;
            __builtin_amdgcn_global_load_lds((const AS1 void*)(A + aoff),
                (AS3 void*)((char*)As + chunk * 16), 16, 0, 0);
        }
        constexpr int QB = BN * 8 / THREADS;
        #pragma unroll
        for (int q = 0; q < QB; ++q) {
            const int chunk = q * THREADS + tid;
            const int row = chunk >> 3;
            const int slot = chunk & 7;
            const int gs = slot ^ (row & 7);
            const size_t boff = (bRow0 + row) * (size_t)Kld + k0 + gs * 8;
            __builtin_amdgcn_global_load_lds((const AS1 void*)(Bt + boff),
                (AS3 void*)((char*)Bs + chunk * 16), 16, 0, 0);
        }
        __syncthreads();

        #pragma unroll
        for (int kk = 0; kk < 2; ++kk) {
            const int sw = ((kk * 4 + (lane >> 4)) ^ (lane & 7)) * 16;
            f16x8 af[M_REP], bf[4];
            #pragma unroll
            for (int i = 0; i < M_REP; ++i) {
                const int row = wm + i * 16 + (lane & 15);
                af[i] = *(const f16x8*)((const char*)As + row * 128 + sw);
            }
            #pragma unroll
            for (int j = 0; j < 4; ++j) {
                const int row = wn + j * 16 + (lane & 15);
                bf[j] = *(const f16x8*)((const char*)Bs + row * 128 + sw);
            }
            #pragma unroll
            for (int i = 0; i < M_REP; ++i)
                #pragma unroll
                for (int j = 0; j < 4; ++j)
                    acc[i][j] = __builtin_amdgcn_mfma_f32_16x16x32_f16(
                        af[i], bf[j], acc[i][j], 0, 0, 0);
        }
        __syncthreads();
    }

    // epilogue: C/D layout col=lane&15, row=(lane>>4)*4+r
    const int col_l = lane & 15, row_l = (lane >> 4) * 4;
    #pragma unroll
    for (int i = 0; i < M_REP; ++i) {
        #pragma unroll
        for (int j = 0; j < 4; ++j) {
            if (EPI == 6) {
                const int col  = bn * BN + wn + j * 16 + col_l;
                const int row0 = bm * BM + wm + i * 16 + row_l;  // 4 consecutive
                const int b = row0 >> 11;
                const int n = row0 & 2047;
                if (col < 1024) {
                    *(fx4*)&Cf[((size_t)b * 1024 + col) * 2048 + n] = acc[i][j];
                } else if (col < 3072) {
                    fx4 partner;
                    #pragma unroll
                    for (int e = 0; e < 4; ++e)
                        partner[e] = __shfl_xor(acc[i][j][e], 1, 64);
                    if ((col & 1) == 0) {
                        fx4 kv;
                        #pragma unroll
                        for (int e = 0; e < 4; ++e) kv[e] = acc[i][j][e] * partner[e];
                        const int hh = (col - 1024) >> 1;
                        *(fx4*)&Cf2[((size_t)b * 1024 + hh) * 2048 + n] = kv;
                    }
                } else if (col < 5120) {
                    fx4 my;
                    #pragma unroll
                    for (int e = 0; e < 4; ++e) my[e] = acc[i][j][e] + bias[col - 3072];
                    fx4 partner;
                    #pragma unroll
                    for (int e = 0; e < 4; ++e)
                        partner[e] = __shfl_xor(my[e], 1, 64);
                    const bool isRe = (col & 1) == 0;
                    const int hh = (col - 3072) >> 1;
                    fx4 o;
                    #pragma unroll
                    for (int e = 0; e < 4; ++e) {
                        const float re = isRe ? my[e] : partner[e];
                        const float im = isRe ? partner[e] : my[e];
                        const float r = sqrtf(re * re + im * im);
                        const float sg = 1.0f / (1.0f + expf(-r));
                        float a_re, a_im;
                        if (r > 0.0f) { const float inv = sg / r; a_re = re * inv; a_im = im * inv; }
                        else          { a_re = sg; a_im = 0.0f; }
                        o[e] = isRe ? a_re : a_im;
                    }
                    if (isRe) *(fx4*)&aRe[((size_t)b * 1024 + hh) * 2048 + n] = o;
                    else      *(fx4*)&aIm[((size_t)b * 1024 + hh) * 2048 + n] = o;
                } else {
                    #pragma unroll
                    for (int r = 0; r < 4; ++r)
                        Ch[(size_t)(row0 + r) * 1024 + (col - 5120)] = (_Float16)acc[i][j][r];
                }
            } else {
                #pragma unroll
                for (int r = 0; r < 4; ++r) {
                    const int row = bm * BM + wm + i * 16 + row_l + r;
                    const int col = bn * BN + wn + j * 16 + col_l;
                    const float v = acc[i][j][r];
                    if (EPI == 0) {
                        Cf[(size_t)row * N + col] = v;
                    } else if (EPI == 2) {
                        Cf[(size_t)row * N + col] += v;
                    } else if (EPI == 4) {
                        const float t = v + bias[col];
                        const float gelu = 0.5f * t * (1.0f + erff(t * 0.70710678118654752f));
                        Ch[(size_t)row * N + col] = (_Float16)gelu;
                    }
                }
            }
        }
    }
}

// ---------------------------------------------------------------- host
extern "C" void kernel_launch(void* const* d_in, const int* in_sizes, int n_in,
                              void* d_out, int out_size, void* d_ws, size_t ws_size,
                              hipStream_t stream)
{
    const int*   tokens = (const int*)d_in[0];
    const float* emb  = (const float*)d_in[1];
    const float* g1   = (const float*)d_in[2];
    const float* Wqkv = (const float*)d_in[3];
    const float* Wa   = (const float*)d_in[4];
    const float* ba   = (const float*)d_in[5];
    const float* Wg   = (const float*)d_in[6];
    const float* Wo   = (const float*)d_in[7];
    const float* g2   = (const float*)d_in[8];
    const float* W1   = (const float*)d_in[9];
    const float* b1   = (const float*)d_in[10];
    const float* W2   = (const float*)d_in[11];
    const float* b2   = (const float*)d_in[12];
    const float* gf   = (const float*)d_in[13];
    const float* Wl   = (const float*)d_in[14];
    float* out = (float*)d_out;

    char* ws = (char*)d_ws;
    size_t off = 0;
    auto take = [&](size_t bytes) {
        char* p = ws + off; off += (bytes + 255) & ~(size_t)255; return p;
    };

    _Float16* wcat = (_Float16*)take((size_t)4 * 6144 * 1024 * 2);
    _Float16* wo   = (_Float16*)take((size_t)4 * 1024 * 1024 * 2);
    _Float16* w1   = (_Float16*)take((size_t)4 * 4096 * 1024 * 2);
    _Float16* w2   = (_Float16*)take((size_t)4 * 1024 * 4096 * 2);
    char*     wlRegion = take((size_t)64 << 20);
    _Float16* wl   = (_Float16*)wlRegion;
    float*    x    = (float*)take((size_t)4096 * 1024 * 4);
    _Float16* xn   = (_Float16*)take((size_t)4096 * 1024 * 2);
    float*    qkvb = (float*)take((size_t)4096 * 3072 * 4);   // h (W1 out)
    float*    alb  = (float*)take((size_t)4096 * 2048 * 4);   // yT / gated / W2 partials
    _Float16* G    = (_Float16*)take((size_t)4096 * 1024 * 2); // gate preact, f16

    float* qT   = (float*)wlRegion;
    float* kvT  = (float*)(wlRegion + ((size_t)16 << 20));
    float* aReT = (float*)(wlRegion + ((size_t)32 << 20));
    float* aImT = (float*)(wlRegion + ((size_t)48 << 20));
    float*    yT    = alb;
    _Float16* gated = (_Float16*)((char*)alb + ((size_t)16 << 20));
    _Float16* h     = (_Float16*)qkvb;
    float*    part  = alb;

    const dim3 blk(256);

    transpose_qkv_kernel<<<dim3(32, 96, 4), blk, 0, stream>>>(Wqkv, wcat);
    transpose_f16_kernel<<<dim3(32,  64, 4), blk, 0, stream>>>(Wa,   wcat + 3072 * 1024, 1024, 2048, (size_t)6144 * 1024);
    transpose_f16_kernel<<<dim3(32,  32, 4), blk, 0, stream>>>(Wg,   wcat + 5120 * 1024, 1024, 1024, (size_t)6144 * 1024);
    transpose_f16_kernel<<<dim3(32,  32, 4), blk, 0, stream>>>(Wo,   wo,  1024, 1024, (size_t)1024 * 1024);
    transpose_f16_kernel<<<dim3(32, 128, 4), blk, 0, stream>>>(W1,   w1,  1024, 4096, (size_t)4096 * 1024);
    transpose_f16_kernel<<<dim3(128, 32, 4), blk, 0, stream>>>(W2,   w2,  4096, 1024, (size_t)1024 * 4096);

    embed_rms_kernel<<<4096, blk, 0, stream>>>(tokens, emb, g1, x, xn);

    for (int i = 0; i < 4; ++i) {
        // fused qkv|a|g GEMM with scan-prep epilogue (G written f16 via Ch)
        gemm_kernel<6, 256, 128, 64><<<dim3(16, 48), dim3(512), 0, stream>>>(
            xn, wcat + (size_t)i * 6144 * 1024, ba + i * 2048,
            qT, kvT, nullptr, aReT, aImT, G, 4096, 6144, 1024, 1024);
        scanT_kernel<<<2048, blk, 0, stream>>>(kvT, aReT, aImT, qT, yT);
        gate_kernel<<<dim3(64, 32, 2), blk, 0, stream>>>(G, yT, gated);
        gemm_kernel<2, 128, 128, 64><<<dim3(32, 8), blk, 0, stream>>>(
            gated, wo + (size_t)i * 1024 * 1024, nullptr,
            x, nullptr, nullptr, nullptr, nullptr, nullptr, 4096, 1024, 1024, 1024);
        rms_f16_kernel<<<4096, blk, 0, stream>>>(x, g2 + i * 1024, xn);
        gemm_kernel<4, 256, 128, 64><<<dim3(16, 32), dim3(512), 0, stream>>>(
            xn, w1 + (size_t)i * 4096 * 1024, b1 + i * 4096,
            nullptr, nullptr, nullptr, nullptr, nullptr, h, 4096, 4096, 1024, 1024);
        gemm_kernel<0, 256, 128, 64><<<dim3(16, 8, 2), dim3(512), 0, stream>>>(
            h, w2 + (size_t)i * 1024 * 4096, nullptr,
            part, nullptr, nullptr, nullptr, nullptr, nullptr, 4096, 1024, 2048, 4096);
        const float* gnext = (i < 3) ? (g1 + (i + 1) * 1024) : gf;
        combine2_rms_kernel<<<4096, blk, 0, stream>>>(part, b2 + i * 1024, gnext, x, xn);
    }

    transpose_f16_kernel<<<dim3(32, 1000, 1), blk, 0, stream>>>(Wl, wl, 1024, 32000, 0);

    // logits: proven 2-barrier kernel
    gemm_kernel<0, 256, 128, 64><<<dim3(16, 250), dim3(512), 0, stream>>>(
        xn, wl, nullptr, out, nullptr, nullptr, nullptr, nullptr, nullptr,
        4096, 32000, 1024, 1024);
}